// Round 5
// baseline (633.987 us; speedup 1.0000x reference)
//
#include <hip/hip_runtime.h>
#include <hip/hip_bf16.h>

typedef __attribute__((ext_vector_type(8))) short short8v;
typedef __attribute__((ext_vector_type(4))) float f32x4;

// U row layout (shorts, stride 448 = 896B):
//   groups of 16 shorts (32B): [8 feats hi | 8 feats lo]
//   aggr part: groups 0..12 (feats 0..99; group 12 tail zero), group 13 = zero pad
//   x    part: groups 14..26 (feats 0..99; group 26 tail zero), group 27 = zero pad
#define USH 448
#define XOFF 224

static __device__ inline unsigned short f2bf(float x) {
    union { float f; unsigned int u; } c; c.f = x;
    unsigned int r = (c.u + 0x7FFFu + ((c.u >> 16) & 1u)) >> 16;
    return (unsigned short)r;
}
static __device__ inline float bf2f(unsigned short h) {
    union { float f; unsigned int u; } c; c.u = ((unsigned int)h) << 16;
    return c.f;
}
static __device__ inline f32x4 MF(short8v a, short8v b, f32x4 c) {
    return __builtin_amdgcn_mfma_f32_16x16x32_bf16(a, b, c, 0, 0, 0);
}

// ---------------- CSR build ----------------

__global__ __launch_bounds__(256) void k_count(const int* __restrict__ key,
                                               int* __restrict__ cnt, int n) {
    int e = blockIdx.x * 256 + threadIdx.x;
    if (e < n) atomicAdd(&cnt[key[e]], 1);
}

__global__ __launch_bounds__(1024) void k_scan1(const int* __restrict__ cnt,
                                                int* __restrict__ rowst,
                                                int* __restrict__ bsum, int n) {
    __shared__ int tmp[1024];
    int t = threadIdx.x;
    int i = blockIdx.x * 1024 + t;
    int v = (i < n) ? cnt[i] : 0;
    tmp[t] = v;
    __syncthreads();
    for (int off = 1; off < 1024; off <<= 1) {
        int u = 0;
        if (t >= off) u = tmp[t - off];
        __syncthreads();
        if (t >= off) tmp[t] += u;
        __syncthreads();
    }
    if (i < n) rowst[i] = tmp[t] - v;
    if (t == 1023) bsum[blockIdx.x] = tmp[1023];
}

// add cross-block prefix in place
__global__ __launch_bounds__(256) void k_fold(int* __restrict__ v,
                                              const int* __restrict__ bsum, int n) {
    int i = blockIdx.x * 256 + threadIdx.x;
    if (i < n) {
        int nb = i >> 10, base = 0;
        for (int j = 0; j < nb; ++j) base += bsum[j];
        v[i] += base;
    }
}

// folds the cross-block prefix and builds cur/inv; sets rowp[n]
__global__ __launch_bounds__(256) void k_scan3(const int* __restrict__ cnt,
                                               int* __restrict__ rowst,
                                               const int* __restrict__ bsum,
                                               int* __restrict__ cur,
                                               float* __restrict__ inv, int n) {
    int i = blockIdx.x * 256 + threadIdx.x;
    if (i < n) {
        int nb = i >> 10;
        int base = 0;
        for (int j = 0; j < nb; ++j) base += bsum[j];
        int r = rowst[i] + base;
        rowst[i] = r;
        cur[i] = r;
        int c = cnt[i];
        inv[i] = 1.0f / (float)(c > 1 ? c : 1);
        if (i == n - 1) rowst[n] = r + c;
    }
}

// scatter edges into src-sorted order (counting sort by src)
__global__ __launch_bounds__(256) void k_scatter_src(const int* __restrict__ src,
                                                     const int* __restrict__ dst,
                                                     int* __restrict__ curS,
                                                     int* __restrict__ es,
                                                     int* __restrict__ ed, int n) {
    int e = blockIdx.x * 256 + threadIdx.x;
    if (e < n) {
        int s = src[e];
        int p = atomicAdd(&curS[s], 1);
        es[p] = s;
        ed[p] = dst[e];
    }
}

// scatter src-sorted edges into dst-CSR: lists end up ~ascending in src
__global__ __launch_bounds__(256) void k_scatter2(const int* __restrict__ es,
                                                  const int* __restrict__ ed,
                                                  int* __restrict__ cur,
                                                  int* __restrict__ ssrc, int n) {
    int e = blockIdx.x * 256 + threadIdx.x;
    if (e < n) {
        int d = ed[e];
        int p = atomicAdd(&cur[d], 1);
        ssrc[p] = es[e];
    }
}

// ---------------- x (fp32) -> interleaved hi/lo into U x-part ----------------
__global__ __launch_bounds__(256) void k_cvt(const float* __restrict__ X,
                                             unsigned short* __restrict__ U, int n) {
    int grp = threadIdx.x >> 5, l = threadIdx.x & 31;
    int i = blockIdx.x * 8 + grp;
    if (i >= n) return;
    unsigned short* row = U + (size_t)i * USH;
    if (l < 13) {
        float f[8];
#pragma unroll
        for (int m = 0; m < 8; ++m) {
            int feat = l * 8 + m;
            f[m] = (feat < 100) ? X[(size_t)i * 100 + feat] : 0.f;
        }
        short8v hv, lv;
#pragma unroll
        for (int m = 0; m < 8; ++m) {
            unsigned short h = f2bf(f[m]);
            hv[m] = (short)h;
            lv[m] = (short)f2bf(f[m] - bf2f(h));
        }
        *(short8v*)(row + XOFF + l * 16) = hv;
        *(short8v*)(row + XOFF + l * 16 + 8) = lv;
    } else if (l == 13) {
        short8v z = (short8v){0,0,0,0,0,0,0,0};
        *(short8v*)(row + XOFF + 13 * 16) = z;
        *(short8v*)(row + XOFF + 13 * 16 + 8) = z;
    }
}

// ---------------- mean aggregation over CSR ----------------
__global__ __launch_bounds__(256) void k_aggr(const unsigned short* __restrict__ U,
                                              const int* __restrict__ ssrc,
                                              const int* __restrict__ rowst,
                                              const float* __restrict__ inv,
                                              unsigned short* __restrict__ O, int n) {
    int grp = threadIdx.x >> 5;
    int l = threadIdx.x & 31;
    int node = blockIdx.x * 8 + grp;
    if (node >= n) return;
    unsigned short* orow = O + (size_t)node * USH;
    if (l == 26 || l == 27) {  // zero aggr pad group 13
        short8v z = (short8v){0,0,0,0,0,0,0,0};
        *(short8v*)(orow + 208 + (l - 26) * 8) = z;
    }
    int s = rowst[node];
    int e = rowst[node + 1];
    const bool act = l < 26;
    float a[8];
#pragma unroll
    for (int m = 0; m < 8; ++m) a[m] = 0.f;
    const size_t loff = XOFF + l * 8;

    int i = s;
    for (; i + 4 <= e; i += 4) {
        int s0 = ssrc[i], s1 = ssrc[i + 1], s2 = ssrc[i + 2], s3 = ssrc[i + 3];
        if (act) {
            short8v v0 = *(const short8v*)(U + (size_t)s0 * USH + loff);
            short8v v1 = *(const short8v*)(U + (size_t)s1 * USH + loff);
            short8v v2 = *(const short8v*)(U + (size_t)s2 * USH + loff);
            short8v v3 = *(const short8v*)(U + (size_t)s3 * USH + loff);
#pragma unroll
            for (int m = 0; m < 8; ++m)
                a[m] += bf2f((unsigned short)v0[m]) + bf2f((unsigned short)v1[m])
                      + bf2f((unsigned short)v2[m]) + bf2f((unsigned short)v3[m]);
        }
    }
    for (; i < e; ++i) {
        int s0 = ssrc[i];
        if (act) {
            short8v v0 = *(const short8v*)(U + (size_t)s0 * USH + loff);
#pragma unroll
            for (int m = 0; m < 8; ++m) a[m] += bf2f((unsigned short)v0[m]);
        }
    }

    const float f = inv[node];
    float tot[8];
#pragma unroll
    for (int m = 0; m < 8; ++m) tot[m] = (a[m] + __shfl_xor(a[m], 1)) * f;

    if (act) {
        short8v w;
        if ((l & 1) == 0) {
#pragma unroll
            for (int m = 0; m < 8; ++m) w[m] = (short)f2bf(tot[m]);
        } else {
#pragma unroll
            for (int m = 0; m < 8; ++m) {
                unsigned short h = f2bf(tot[m]);
                w[m] = (short)f2bf(tot[m] - bf2f(h));
            }
        }
        *(short8v*)(orow + (l >> 1) * 16 + (l & 1) * 8) = w;
    }
}

// ---------------- weight pack ----------------
static __device__ inline float wsrc(const float* Wl, const float* Wr,
                                    int G, int jj, int col) {
    if (col >= 100) return 0.f;
    if (G <= 12) { int f = 8 * G + jj; return (f < 100) ? Wl[f * 100 + col] : 0.f; }
    if (G >= 14 && G <= 26) { int f = 8 * (G - 14) + jj; return (f < 100) ? Wr[f * 100 + col] : 0.f; }
    return 0.f;
}

__global__ __launch_bounds__(256) void k_pack(const float* __restrict__ Wl,
                                              const float* __restrict__ Wr,
                                              unsigned short* __restrict__ B13,
                                              unsigned short* __restrict__ B2) {
    int idx = blockIdx.x * 256 + threadIdx.x;
    const int n13 = 14 * 7 * 64;
    const int n2 = 7 * 7 * 64;
    if (idx < n13) {
        int lane = idx & 63;
        int t = idx >> 6;
        int nt = t % 7, cp = t / 7;
        int lg = lane >> 4;
        int col = nt * 16 + (lane & 15);
        int G = 2 * cp + (lg >> 1);
        for (int jj = 0; jj < 8; ++jj) {
            float w = wsrc(Wl, Wr, G, jj, col);
            B13[(size_t)idx * 8 + jj] = f2bf(w);
        }
    } else if (idx < n13 + n2) {
        int j2 = idx - n13;
        int lane = j2 & 63;
        int t = j2 >> 6;
        int nt = t % 7, c = t / 7;
        int lg = lane >> 4;
        int col = nt * 16 + (lane & 15);
        int G = 4 * c + lg;
        for (int jj = 0; jj < 8; ++jj) {
            float w = wsrc(Wl, Wr, G, jj, col);
            unsigned short h = f2bf(w);
            B2[(size_t)j2 * 8 + jj] = f2bf(w - bf2f(h));
        }
    }
}

// ---------------- MFMA GEMM: Out.x-part = act(U @ [Wl;Wr] + b) --------------
__global__ __launch_bounds__(256) void k_gemm(const unsigned short* __restrict__ U,
                                              const unsigned short* __restrict__ B13,
                                              const unsigned short* __restrict__ B2,
                                              const float* __restrict__ bias,
                                              unsigned short* __restrict__ Out,
                                              int relu, int n, int ntasks) {
    const int lane = threadIdx.x & 63;
    const int wv = threadIdx.x >> 6;
    const int task = blockIdx.x * 4 + wv;
    if (task >= ntasks) return;
    const int m0 = task * 32;
    const int lrow = lane & 15;
    const int lg = lane >> 4;

    f32x4 acc[2][7];
#pragma unroll
    for (int mt = 0; mt < 2; ++mt)
#pragma unroll
        for (int nt = 0; nt < 7; ++nt) acc[mt][nt] = (f32x4){0.f, 0.f, 0.f, 0.f};

    int r0 = m0 + lrow;      if (r0 >= n) r0 = n - 1;
    int r1 = m0 + 16 + lrow; if (r1 >= n) r1 = n - 1;
    const size_t ub0 = (size_t)r0 * USH + lg * 8;
    const size_t ub1 = (size_t)r1 * USH + lg * 8;
    const size_t xb0 = (size_t)r0 * USH + lg * 16;
    const size_t xb1 = (size_t)r1 * USH + lg * 16;

#pragma unroll
    for (int c = 0; c < 14; ++c) {
        short8v a0 = *(const short8v*)(U + ub0 + c * 32);
        short8v a1 = *(const short8v*)(U + ub1 + c * 32);
        const unsigned short* bp = B13 + ((size_t)(c * 7) * 64 + lane) * 8;
#pragma unroll
        for (int nt = 0; nt < 7; ++nt) {
            short8v b = *(const short8v*)(bp + nt * 512);
            acc[0][nt] = MF(a0, b, acc[0][nt]);
            acc[1][nt] = MF(a1, b, acc[1][nt]);
        }
    }
#pragma unroll
    for (int c = 0; c < 7; ++c) {
        short8v a0 = *(const short8v*)(U + xb0 + c * 64);
        short8v a1 = *(const short8v*)(U + xb1 + c * 64);
        const unsigned short* bp = B2 + ((size_t)(c * 7) * 64 + lane) * 8;
#pragma unroll
        for (int nt = 0; nt < 7; ++nt) {
            short8v b = *(const short8v*)(bp + nt * 512);
            acc[0][nt] = MF(a0, b, acc[0][nt]);
            acc[1][nt] = MF(a1, b, acc[1][nt]);
        }
    }

#pragma unroll
    for (int nt = 0; nt < 7; ++nt) {
        int col = nt * 16 + lrow;
        bool cok = col < 100;
        float bb = cok ? bias[cok ? col : 0] : 0.f;
        int gsh = (14 + (col >> 3)) * 16 + (col & 7);
#pragma unroll
        for (int mt = 0; mt < 2; ++mt) {
#pragma unroll
            for (int r = 0; r < 4; ++r) {
                int row = m0 + mt * 16 + lg * 4 + r;
                if (cok && row < n) {
                    float v = acc[mt][nt][r] + bb;
                    if (relu) v = fmaxf(v, 0.f);
                    unsigned short h = f2bf(v);
                    unsigned short lo = f2bf(v - bf2f(h));
                    unsigned short* orow = Out + (size_t)row * USH;
                    orow[gsh] = h;
                    orow[gsh + 8] = lo;
                }
            }
        }
    }
    {
        int row = m0 + (lane >> 1);
        if (row < n) {
            unsigned short* orow = Out + (size_t)row * USH;
            if ((lane & 1) == 0) {
                short4 z4 = {0, 0, 0, 0};
                *(short4*)(orow + 420) = z4;
                *(short4*)(orow + 428) = z4;
            } else {
                short8v z = (short8v){0,0,0,0,0,0,0,0};
                *(short8v*)(orow + 432) = z;
                *(short8v*)(orow + 440) = z;
            }
        }
    }
}

// ---------------- pool stage 1: node-parallel per-graph partial sums --------
// 128 nodes/block, 8 lane-groups; per-graph accum in LDS (batch sorted =>
// few graphs per block), then one global atomicAdd per (graph, feat).
#define PN 128
__global__ __launch_bounds__(256) void k_pool1(const unsigned short* __restrict__ U,
                                               const int* __restrict__ batch,
                                               float* __restrict__ gs, int n) {
    __shared__ float acc[32][104];
    int n0 = blockIdx.x * PN;
    int t = threadIdx.x;
    int grp = t >> 5, l = t & 31;
    int nend = n0 + PN; if (nend > n) nend = n;
    int gmin = batch[n0];
    int gmax = batch[nend - 1];
    int span = gmax - gmin + 1;
    const bool act = l < 26;
    const int fbase = (l >> 1) * 8;

    if (span <= 32) {
        for (int i = t; i < 32 * 104; i += 256) ((float*)acc)[i] = 0.f;
        __syncthreads();
        for (int node = n0 + grp; node < nend; node += 8) {
            if (act) {
                int g = batch[node] - gmin;
                short8v v = *(const short8v*)(U + (size_t)node * USH + XOFF + l * 8);
#pragma unroll
                for (int m = 0; m < 8; ++m)
                    atomicAdd(&acc[g][fbase + m], bf2f((unsigned short)v[m]));
            }
        }
        __syncthreads();
        for (int i = t; i < span * 104; i += 256) {
            int g = i / 104, f = i - g * 104;
            atomicAdd(&gs[(size_t)(gmin + g) * 104 + f], acc[g][f]);
        }
    } else {  // degenerate fallback (not expected)
        for (int node = n0 + grp; node < nend; node += 8) {
            if (act) {
                int g = batch[node];
                short8v v = *(const short8v*)(U + (size_t)node * USH + XOFF + l * 8);
#pragma unroll
                for (int m = 0; m < 8; ++m)
                    atomicAdd(&gs[(size_t)g * 104 + fbase + m], bf2f((unsigned short)v[m]));
            }
        }
    }
}

// ---------------- pool stage 2: divide by count + linear head ----------------
__global__ __launch_bounds__(128) void k_pool2(const float* __restrict__ gs,
                                               const int* __restrict__ batch,
                                               const float* __restrict__ Wlin,
                                               const float* __restrict__ blin,
                                               float* __restrict__ out, int n) {
    int g = blockIdx.x;
    int t = threadIdx.x;
    int lo = 0, hi = n;
    while (lo < hi) { int m = (lo + hi) >> 1; if (batch[m] < g) lo = m + 1; else hi = m; }
    int lo2 = lo, hi2 = n;
    while (lo2 < hi2) { int m = (lo2 + hi2) >> 1; if (batch[m] < g + 1) lo2 = m + 1; else hi2 = m; }

    __shared__ float gm[100];
    float f = (lo2 > lo) ? 1.0f / (float)(lo2 - lo) : 0.0f;
    if (t < 100) gm[t] = gs[(size_t)g * 104 + t] * f;
    __syncthreads();
    if (t < 2) {
        float o = blin[t];
        for (int k = 0; k < 100; ++k) o += gm[k] * Wlin[k * 2 + t];
        out[g * 2 + t] = o;
    }
}

// ---------------- launch ----------------

extern "C" void kernel_launch(void* const* d_in, const int* in_sizes, int n_in,
                              void* d_out, int out_size, void* d_ws, size_t ws_size,
                              hipStream_t stream) {
    const float* x    = (const float*)d_in[0];
    const int*   ei   = (const int*)d_in[1];
    const int*   batch= (const int*)d_in[2];
    const float* W1l  = (const float*)d_in[3];
    const float* b1   = (const float*)d_in[4];
    const float* W1r  = (const float*)d_in[5];
    const float* W2l  = (const float*)d_in[6];
    const float* b2   = (const float*)d_in[7];
    const float* W2r  = (const float*)d_in[8];
    const float* W3l  = (const float*)d_in[9];
    const float* b3   = (const float*)d_in[10];
    const float* W3r  = (const float*)d_in[11];
    const float* Wlin = (const float*)d_in[12];
    const float* blin = (const float*)d_in[13];
    float* out = (float*)d_out;

    const int n_nodes  = in_sizes[0] / 100;
    const int n_edges  = in_sizes[1] / 2;
    const int n_graphs = out_size / 2;
    const int* src = ei;
    const int* dst = ei + n_edges;

    char* ws = (char*)d_ws;
    size_t o = 0;
    auto alloc = [&](size_t bytes) { size_t r = o; o = (o + bytes + 255) & ~(size_t)255; return r; };
    int*   cnt  = (int*)(ws + alloc((size_t)n_nodes * 4));
    int*   cntS = (int*)(ws + alloc((size_t)n_nodes * 4));
    int*   curS = (int*)(ws + alloc((size_t)n_nodes * 4));
    int*   rowp = (int*)(ws + alloc((size_t)(n_nodes + 1) * 4));
    int*   cur  = (int*)(ws + alloc((size_t)n_nodes * 4));
    int*   bsum = (int*)(ws + alloc(64 * 4));
    float* inv  = (float*)(ws + alloc((size_t)n_nodes * 4));
    int*   ssrc = (int*)(ws + alloc((size_t)n_edges * 4));
    float* gs   = (float*)(ws + alloc((size_t)n_graphs * 104 * 4));
    const size_t ubytes = (size_t)n_nodes * USH * 2;
    unsigned short* UA = (unsigned short*)(ws + alloc(ubytes));
    unsigned short* UB = (unsigned short*)(ws + alloc(ubytes));
    const size_t b13b = (size_t)14 * 7 * 64 * 8 * 2;
    const size_t b2b  = (size_t)7 * 7 * 64 * 8 * 2;
    unsigned short* P1a = (unsigned short*)(ws + alloc(b13b));
    unsigned short* P1b = (unsigned short*)(ws + alloc(b2b));
    unsigned short* P2a = (unsigned short*)(ws + alloc(b13b));
    unsigned short* P2b = (unsigned short*)(ws + alloc(b2b));
    unsigned short* P3a = (unsigned short*)(ws + alloc(b13b));
    unsigned short* P3b = (unsigned short*)(ws + alloc(b2b));
    // es/ed alias UB: only used during CSR build, before UB's first write (gemm1)
    int* es = (int*)UB;
    int* ed = es + n_edges;

    hipMemsetAsync(cnt, 0, (size_t)n_nodes * 4, stream);
    hipMemsetAsync(cntS, 0, (size_t)n_nodes * 4, stream);
    hipMemsetAsync(gs, 0, (size_t)n_graphs * 104 * 4, stream);

    const int eb = (n_edges + 255) / 256;
    const int sb = (n_nodes + 1023) / 1024;
    const int nb256 = (n_nodes + 255) / 256;

    // counting sort edges by src (for gather locality in k_aggr)
    k_count<<<eb, 256, 0, stream>>>(src, cntS, n_edges);
    k_scan1<<<sb, 1024, 0, stream>>>(cntS, curS, bsum, n_nodes);
    k_fold<<<nb256, 256, 0, stream>>>(curS, bsum, n_nodes);
    k_scatter_src<<<eb, 256, 0, stream>>>(src, dst, curS, es, ed, n_edges);
    // dst-CSR over src-sorted edges
    k_count<<<eb, 256, 0, stream>>>(dst, cnt, n_edges);
    k_scan1<<<sb, 1024, 0, stream>>>(cnt, rowp, bsum, n_nodes);
    k_scan3<<<nb256, 256, 0, stream>>>(cnt, rowp, bsum, cur, inv, n_nodes);
    k_scatter2<<<eb, 256, 0, stream>>>(es, ed, cur, ssrc, n_edges);

    const int pkb = (14 * 7 * 64 + 7 * 7 * 64 + 255) / 256;
    k_pack<<<pkb, 256, 0, stream>>>(W1l, W1r, P1a, P1b);
    k_pack<<<pkb, 256, 0, stream>>>(W2l, W2r, P2a, P2b);
    k_pack<<<pkb, 256, 0, stream>>>(W3l, W3r, P3a, P3b);

    const int ab = (n_nodes + 7) / 8;
    const int ntasks = (n_nodes + 31) / 32;
    const int ggrid = (ntasks + 3) / 4;

    k_cvt<<<ab, 256, 0, stream>>>(x, UA, n_nodes);

    // layer 1: UA.aggr = mean(UA.x); UB.x = relu(UA @ [W1l;W1r] + b1)
    k_aggr<<<ab, 256, 0, stream>>>(UA, ssrc, rowp, inv, UA, n_nodes);
    k_gemm<<<ggrid, 256, 0, stream>>>(UA, P1a, P1b, b1, UB, 1, n_nodes, ntasks);
    // layer 2
    k_aggr<<<ab, 256, 0, stream>>>(UB, ssrc, rowp, inv, UB, n_nodes);
    k_gemm<<<ggrid, 256, 0, stream>>>(UB, P2a, P2b, b2, UA, 1, n_nodes, ntasks);
    // layer 3 (no relu)
    k_aggr<<<ab, 256, 0, stream>>>(UA, ssrc, rowp, inv, UA, n_nodes);
    k_gemm<<<ggrid, 256, 0, stream>>>(UA, P3a, P3b, b3, UB, 0, n_nodes, ntasks);

    const int pb1 = (n_nodes + PN - 1) / PN;
    k_pool1<<<pb1, 256, 0, stream>>>(UB, batch, gs, n_nodes);
    k_pool2<<<n_graphs, 128, 0, stream>>>(gs, batch, Wlin, blin, out, n_nodes);
}

// Round 6
// 474.352 us; speedup vs baseline: 1.3365x; 1.3365x over previous
//
#include <hip/hip_runtime.h>
#include <hip/hip_bf16.h>

typedef __attribute__((ext_vector_type(8))) short short8v;
typedef __attribute__((ext_vector_type(4))) float f32x4;

// U row layout (shorts, stride 448 = 896B):
//   groups of 16 shorts (32B): [8 feats hi | 8 feats lo]
//   aggr part: groups 0..12 (feats 0..99; group 12 tail zero), group 13 = zero pad
//   x    part: groups 14..26 (feats 0..99; group 26 tail zero), group 27 = zero pad
#define USH 448
#define XOFF 224

static __device__ inline unsigned short f2bf(float x) {
    union { float f; unsigned int u; } c; c.f = x;
    unsigned int r = (c.u + 0x7FFFu + ((c.u >> 16) & 1u)) >> 16;
    return (unsigned short)r;
}
static __device__ inline float bf2f(unsigned short h) {
    union { float f; unsigned int u; } c; c.u = ((unsigned int)h) << 16;
    return c.f;
}
static __device__ inline f32x4 MF(short8v a, short8v b, f32x4 c) {
    return __builtin_amdgcn_mfma_f32_16x16x32_bf16(a, b, c, 0, 0, 0);
}

// ---------------- CSR build ----------------

__global__ __launch_bounds__(256) void k_count(const int* __restrict__ key,
                                               int* __restrict__ cnt, int n) {
    int e = blockIdx.x * 256 + threadIdx.x;
    if (e < n) atomicAdd(&cnt[key[e]], 1);
}

__global__ __launch_bounds__(1024) void k_scan1(const int* __restrict__ cnt,
                                                int* __restrict__ rowst,
                                                int* __restrict__ bsum, int n) {
    __shared__ int tmp[1024];
    int t = threadIdx.x;
    int i = blockIdx.x * 1024 + t;
    int v = (i < n) ? cnt[i] : 0;
    tmp[t] = v;
    __syncthreads();
    for (int off = 1; off < 1024; off <<= 1) {
        int u = 0;
        if (t >= off) u = tmp[t - off];
        __syncthreads();
        if (t >= off) tmp[t] += u;
        __syncthreads();
    }
    if (i < n) rowst[i] = tmp[t] - v;
    if (t == 1023) bsum[blockIdx.x] = tmp[1023];
}

// folds the cross-block prefix and builds cur/inv; sets rowp[n]
__global__ __launch_bounds__(256) void k_scan3(const int* __restrict__ cnt,
                                               int* __restrict__ rowst,
                                               const int* __restrict__ bsum,
                                               int* __restrict__ cur,
                                               float* __restrict__ inv, int n) {
    int i = blockIdx.x * 256 + threadIdx.x;
    if (i < n) {
        int nb = i >> 10;
        int base = 0;
        for (int j = 0; j < nb; ++j) base += bsum[j];
        int r = rowst[i] + base;
        rowst[i] = r;
        cur[i] = r;
        int c = cnt[i];
        inv[i] = 1.0f / (float)(c > 1 ? c : 1);
        if (i == n - 1) rowst[n] = r + c;
    }
}

__global__ __launch_bounds__(256) void k_scatter(const int* __restrict__ src,
                                                 const int* __restrict__ dst,
                                                 int* __restrict__ cur,
                                                 int* __restrict__ ssrc, int n) {
    int e = blockIdx.x * 256 + threadIdx.x;
    if (e < n) {
        int d = dst[e];
        int p = atomicAdd(&cur[d], 1);
        ssrc[p] = src[e];
    }
}

// ---------------- x (fp32) -> interleaved hi/lo into U x-part ----------------
__global__ __launch_bounds__(256) void k_cvt(const float* __restrict__ X,
                                             unsigned short* __restrict__ U, int n) {
    int grp = threadIdx.x >> 5, l = threadIdx.x & 31;
    int i = blockIdx.x * 8 + grp;
    if (i >= n) return;
    unsigned short* row = U + (size_t)i * USH;
    if (l < 13) {
        float f[8];
#pragma unroll
        for (int m = 0; m < 8; ++m) {
            int feat = l * 8 + m;
            f[m] = (feat < 100) ? X[(size_t)i * 100 + feat] : 0.f;
        }
        short8v hv, lv;
#pragma unroll
        for (int m = 0; m < 8; ++m) {
            unsigned short h = f2bf(f[m]);
            hv[m] = (short)h;
            lv[m] = (short)f2bf(f[m] - bf2f(h));
        }
        *(short8v*)(row + XOFF + l * 16) = hv;
        *(short8v*)(row + XOFF + l * 16 + 8) = lv;
    } else if (l == 13) {
        short8v z = (short8v){0,0,0,0,0,0,0,0};
        *(short8v*)(row + XOFF + 13 * 16) = z;
        *(short8v*)(row + XOFF + 13 * 16 + 8) = z;
    }
}

// ---------------- mean aggregation over CSR ----------------
__global__ __launch_bounds__(256) void k_aggr(const unsigned short* __restrict__ U,
                                              const int* __restrict__ ssrc,
                                              const int* __restrict__ rowst,
                                              const float* __restrict__ inv,
                                              unsigned short* __restrict__ O, int n) {
    int grp = threadIdx.x >> 5;
    int l = threadIdx.x & 31;
    int node = blockIdx.x * 8 + grp;
    if (node >= n) return;
    unsigned short* orow = O + (size_t)node * USH;
    if (l == 26 || l == 27) {  // zero aggr pad group 13
        short8v z = (short8v){0,0,0,0,0,0,0,0};
        *(short8v*)(orow + 208 + (l - 26) * 8) = z;
    }
    int s = rowst[node];
    int e = rowst[node + 1];
    const bool act = l < 26;
    float a[8];
#pragma unroll
    for (int m = 0; m < 8; ++m) a[m] = 0.f;
    const size_t loff = XOFF + l * 8;

    int i = s;
    for (; i + 4 <= e; i += 4) {
        int s0 = ssrc[i], s1 = ssrc[i + 1], s2 = ssrc[i + 2], s3 = ssrc[i + 3];
        if (act) {
            short8v v0 = *(const short8v*)(U + (size_t)s0 * USH + loff);
            short8v v1 = *(const short8v*)(U + (size_t)s1 * USH + loff);
            short8v v2 = *(const short8v*)(U + (size_t)s2 * USH + loff);
            short8v v3 = *(const short8v*)(U + (size_t)s3 * USH + loff);
#pragma unroll
            for (int m = 0; m < 8; ++m)
                a[m] += bf2f((unsigned short)v0[m]) + bf2f((unsigned short)v1[m])
                      + bf2f((unsigned short)v2[m]) + bf2f((unsigned short)v3[m]);
        }
    }
    for (; i < e; ++i) {
        int s0 = ssrc[i];
        if (act) {
            short8v v0 = *(const short8v*)(U + (size_t)s0 * USH + loff);
#pragma unroll
            for (int m = 0; m < 8; ++m) a[m] += bf2f((unsigned short)v0[m]);
        }
    }

    const float f = inv[node];
    float tot[8];
#pragma unroll
    for (int m = 0; m < 8; ++m) tot[m] = (a[m] + __shfl_xor(a[m], 1)) * f;

    if (act) {
        short8v w;
        if ((l & 1) == 0) {
#pragma unroll
            for (int m = 0; m < 8; ++m) w[m] = (short)f2bf(tot[m]);
        } else {
#pragma unroll
            for (int m = 0; m < 8; ++m) {
                unsigned short h = f2bf(tot[m]);
                w[m] = (short)f2bf(tot[m] - bf2f(h));
            }
        }
        *(short8v*)(orow + (l >> 1) * 16 + (l & 1) * 8) = w;
    }
}

// ---------------- weight pack ----------------
static __device__ inline float wsrc(const float* Wl, const float* Wr,
                                    int G, int jj, int col) {
    if (col >= 100) return 0.f;
    if (G <= 12) { int f = 8 * G + jj; return (f < 100) ? Wl[f * 100 + col] : 0.f; }
    if (G >= 14 && G <= 26) { int f = 8 * (G - 14) + jj; return (f < 100) ? Wr[f * 100 + col] : 0.f; }
    return 0.f;
}

__global__ __launch_bounds__(256) void k_pack(const float* __restrict__ Wl,
                                              const float* __restrict__ Wr,
                                              unsigned short* __restrict__ B13,
                                              unsigned short* __restrict__ B2) {
    int idx = blockIdx.x * 256 + threadIdx.x;
    const int n13 = 14 * 7 * 64;
    const int n2 = 7 * 7 * 64;
    if (idx < n13) {
        int lane = idx & 63;
        int t = idx >> 6;
        int nt = t % 7, cp = t / 7;
        int lg = lane >> 4;
        int col = nt * 16 + (lane & 15);
        int G = 2 * cp + (lg >> 1);
        for (int jj = 0; jj < 8; ++jj) {
            float w = wsrc(Wl, Wr, G, jj, col);
            B13[(size_t)idx * 8 + jj] = f2bf(w);
        }
    } else if (idx < n13 + n2) {
        int j2 = idx - n13;
        int lane = j2 & 63;
        int t = j2 >> 6;
        int nt = t % 7, c = t / 7;
        int lg = lane >> 4;
        int col = nt * 16 + (lane & 15);
        int G = 4 * c + lg;
        for (int jj = 0; jj < 8; ++jj) {
            float w = wsrc(Wl, Wr, G, jj, col);
            unsigned short h = f2bf(w);
            B2[(size_t)j2 * 8 + jj] = f2bf(w - bf2f(h));
        }
    }
}

// ---------------- MFMA GEMM: Out.x-part = act(U @ [Wl;Wr] + b) --------------
__global__ __launch_bounds__(256) void k_gemm(const unsigned short* __restrict__ U,
                                              const unsigned short* __restrict__ B13,
                                              const unsigned short* __restrict__ B2,
                                              const float* __restrict__ bias,
                                              unsigned short* __restrict__ Out,
                                              int relu, int n, int ntasks) {
    const int lane = threadIdx.x & 63;
    const int wv = threadIdx.x >> 6;
    const int task = blockIdx.x * 4 + wv;
    if (task >= ntasks) return;
    const int m0 = task * 32;
    const int lrow = lane & 15;
    const int lg = lane >> 4;

    f32x4 acc[2][7];
#pragma unroll
    for (int mt = 0; mt < 2; ++mt)
#pragma unroll
        for (int nt = 0; nt < 7; ++nt) acc[mt][nt] = (f32x4){0.f, 0.f, 0.f, 0.f};

    int r0 = m0 + lrow;      if (r0 >= n) r0 = n - 1;
    int r1 = m0 + 16 + lrow; if (r1 >= n) r1 = n - 1;
    const size_t ub0 = (size_t)r0 * USH + lg * 8;
    const size_t ub1 = (size_t)r1 * USH + lg * 8;
    const size_t xb0 = (size_t)r0 * USH + lg * 16;
    const size_t xb1 = (size_t)r1 * USH + lg * 16;

#pragma unroll
    for (int c = 0; c < 14; ++c) {
        short8v a0 = *(const short8v*)(U + ub0 + c * 32);
        short8v a1 = *(const short8v*)(U + ub1 + c * 32);
        const unsigned short* bp = B13 + ((size_t)(c * 7) * 64 + lane) * 8;
#pragma unroll
        for (int nt = 0; nt < 7; ++nt) {
            short8v b = *(const short8v*)(bp + nt * 512);
            acc[0][nt] = MF(a0, b, acc[0][nt]);
            acc[1][nt] = MF(a1, b, acc[1][nt]);
        }
    }
#pragma unroll
    for (int c = 0; c < 7; ++c) {
        short8v a0 = *(const short8v*)(U + xb0 + c * 64);
        short8v a1 = *(const short8v*)(U + xb1 + c * 64);
        const unsigned short* bp = B2 + ((size_t)(c * 7) * 64 + lane) * 8;
#pragma unroll
        for (int nt = 0; nt < 7; ++nt) {
            short8v b = *(const short8v*)(bp + nt * 512);
            acc[0][nt] = MF(a0, b, acc[0][nt]);
            acc[1][nt] = MF(a1, b, acc[1][nt]);
        }
    }

#pragma unroll
    for (int nt = 0; nt < 7; ++nt) {
        int col = nt * 16 + lrow;
        bool cok = col < 100;
        float bb = cok ? bias[cok ? col : 0] : 0.f;
        int gsh = (14 + (col >> 3)) * 16 + (col & 7);
#pragma unroll
        for (int mt = 0; mt < 2; ++mt) {
#pragma unroll
            for (int r = 0; r < 4; ++r) {
                int row = m0 + mt * 16 + lg * 4 + r;
                if (cok && row < n) {
                    float v = acc[mt][nt][r] + bb;
                    if (relu) v = fmaxf(v, 0.f);
                    unsigned short h = f2bf(v);
                    unsigned short lo = f2bf(v - bf2f(h));
                    unsigned short* orow = Out + (size_t)row * USH;
                    orow[gsh] = h;
                    orow[gsh + 8] = lo;
                }
            }
        }
    }
    {
        int row = m0 + (lane >> 1);
        if (row < n) {
            unsigned short* orow = Out + (size_t)row * USH;
            if ((lane & 1) == 0) {
                short4 z4 = {0, 0, 0, 0};
                *(short4*)(orow + 420) = z4;
                *(short4*)(orow + 428) = z4;
            } else {
                short8v z = (short8v){0,0,0,0,0,0,0,0};
                *(short8v*)(orow + 432) = z;
                *(short8v*)(orow + 440) = z;
            }
        }
    }
}

// ---------------- pool + head: 1 block/graph, aggr-style vector loads -------
// 8 lane-groups stride the graph's node range; lane pairs (2k,2k+1) cover
// feats 8k..8k+7 (hi|lo halves); plain-store LDS tree reduce; fused head.
__global__ __launch_bounds__(256) void k_pool(const unsigned short* __restrict__ U,
                                              const int* __restrict__ batch,
                                              const float* __restrict__ Wlin,
                                              const float* __restrict__ blin,
                                              float* __restrict__ out, int n) {
    int g = blockIdx.x;
    int t = threadIdx.x;
    int grp = t >> 5, l = t & 31;
    int lo = 0, hi = n;
    while (lo < hi) { int m = (lo + hi) >> 1; if (batch[m] < g) lo = m + 1; else hi = m; }
    int lo2 = lo, hi2 = n;
    while (lo2 < hi2) { int m = (lo2 + hi2) >> 1; if (batch[m] < g + 1) lo2 = m + 1; else hi2 = m; }

    const bool act = l < 26;
    float a[8];
#pragma unroll
    for (int m = 0; m < 8; ++m) a[m] = 0.f;
    const size_t loff = XOFF + l * 8;
    for (int node = lo + grp; node < lo2; node += 8) {
        if (act) {
            short8v v = *(const short8v*)(U + (size_t)node * USH + loff);
#pragma unroll
            for (int m = 0; m < 8; ++m) a[m] += bf2f((unsigned short)v[m]);
        }
    }
    // pair-combine hi+lo halves: both lanes of a pair then hold feats (l>>1)*8+m
#pragma unroll
    for (int m = 0; m < 8; ++m) a[m] += __shfl_xor(a[m], 1);

    __shared__ float part[8][13][8];
    if (act && (l & 1) == 0) {
#pragma unroll
        for (int m = 0; m < 8; ++m) part[grp][l >> 1][m] = a[m];
    }
    __syncthreads();

    __shared__ float gm[104];
    if (t < 104) {  // t == feat index (fg*8+m)
        int fg = t >> 3, m = t & 7;
        float s = 0.f;
#pragma unroll
        for (int q = 0; q < 8; ++q) s += part[q][fg][m];
        float f = (lo2 > lo) ? 1.0f / (float)(lo2 - lo) : 0.0f;
        gm[t] = s * f;
    }
    __syncthreads();
    if (t < 2) {
        float o = blin[t];
        for (int k = 0; k < 100; ++k) o += gm[k] * Wlin[k * 2 + t];
        out[g * 2 + t] = o;
    }
}

// ---------------- launch ----------------

extern "C" void kernel_launch(void* const* d_in, const int* in_sizes, int n_in,
                              void* d_out, int out_size, void* d_ws, size_t ws_size,
                              hipStream_t stream) {
    const float* x    = (const float*)d_in[0];
    const int*   ei   = (const int*)d_in[1];
    const int*   batch= (const int*)d_in[2];
    const float* W1l  = (const float*)d_in[3];
    const float* b1   = (const float*)d_in[4];
    const float* W1r  = (const float*)d_in[5];
    const float* W2l  = (const float*)d_in[6];
    const float* b2   = (const float*)d_in[7];
    const float* W2r  = (const float*)d_in[8];
    const float* W3l  = (const float*)d_in[9];
    const float* b3   = (const float*)d_in[10];
    const float* W3r  = (const float*)d_in[11];
    const float* Wlin = (const float*)d_in[12];
    const float* blin = (const float*)d_in[13];
    float* out = (float*)d_out;

    const int n_nodes  = in_sizes[0] / 100;
    const int n_edges  = in_sizes[1] / 2;
    const int n_graphs = out_size / 2;
    const int* src = ei;
    const int* dst = ei + n_edges;

    char* ws = (char*)d_ws;
    size_t o = 0;
    auto alloc = [&](size_t bytes) { size_t r = o; o = (o + bytes + 255) & ~(size_t)255; return r; };
    int*   cnt  = (int*)(ws + alloc((size_t)n_nodes * 4));
    int*   rowp = (int*)(ws + alloc((size_t)(n_nodes + 1) * 4));
    int*   cur  = (int*)(ws + alloc((size_t)n_nodes * 4));
    int*   bsum = (int*)(ws + alloc(64 * 4));
    float* inv  = (float*)(ws + alloc((size_t)n_nodes * 4));
    int*   ssrc = (int*)(ws + alloc((size_t)n_edges * 4));
    const size_t ubytes = (size_t)n_nodes * USH * 2;
    unsigned short* UA = (unsigned short*)(ws + alloc(ubytes));
    unsigned short* UB = (unsigned short*)(ws + alloc(ubytes));
    const size_t b13b = (size_t)14 * 7 * 64 * 8 * 2;
    const size_t b2b  = (size_t)7 * 7 * 64 * 8 * 2;
    unsigned short* P1a = (unsigned short*)(ws + alloc(b13b));
    unsigned short* P1b = (unsigned short*)(ws + alloc(b2b));
    unsigned short* P2a = (unsigned short*)(ws + alloc(b13b));
    unsigned short* P2b = (unsigned short*)(ws + alloc(b2b));
    unsigned short* P3a = (unsigned short*)(ws + alloc(b13b));
    unsigned short* P3b = (unsigned short*)(ws + alloc(b2b));

    hipMemsetAsync(cnt, 0, (size_t)n_nodes * 4, stream);

    const int eb = (n_edges + 255) / 256;
    const int sb = (n_nodes + 1023) / 1024;
    const int nb256 = (n_nodes + 255) / 256;

    k_count<<<eb, 256, 0, stream>>>(dst, cnt, n_edges);
    k_scan1<<<sb, 1024, 0, stream>>>(cnt, rowp, bsum, n_nodes);
    k_scan3<<<nb256, 256, 0, stream>>>(cnt, rowp, bsum, cur, inv, n_nodes);
    k_scatter<<<eb, 256, 0, stream>>>(src, dst, cur, ssrc, n_edges);

    const int pkb = (14 * 7 * 64 + 7 * 7 * 64 + 255) / 256;
    k_pack<<<pkb, 256, 0, stream>>>(W1l, W1r, P1a, P1b);
    k_pack<<<pkb, 256, 0, stream>>>(W2l, W2r, P2a, P2b);
    k_pack<<<pkb, 256, 0, stream>>>(W3l, W3r, P3a, P3b);

    const int ab = (n_nodes + 7) / 8;
    const int ntasks = (n_nodes + 31) / 32;
    const int ggrid = (ntasks + 3) / 4;

    k_cvt<<<ab, 256, 0, stream>>>(x, UA, n_nodes);

    // layer 1: UA.aggr = mean(UA.x); UB.x = relu(UA @ [W1l;W1r] + b1)
    k_aggr<<<ab, 256, 0, stream>>>(UA, ssrc, rowp, inv, UA, n_nodes);
    k_gemm<<<ggrid, 256, 0, stream>>>(UA, P1a, P1b, b1, UB, 1, n_nodes, ntasks);
    // layer 2
    k_aggr<<<ab, 256, 0, stream>>>(UB, ssrc, rowp, inv, UB, n_nodes);
    k_gemm<<<ggrid, 256, 0, stream>>>(UB, P2a, P2b, b2, UA, 1, n_nodes, ntasks);
    // layer 3 (no relu)
    k_aggr<<<ab, 256, 0, stream>>>(UA, ssrc, rowp, inv, UA, n_nodes);
    k_gemm<<<ggrid, 256, 0, stream>>>(UA, P3a, P3b, b3, UB, 0, n_nodes, ntasks);

    k_pool<<<n_graphs, 256, 0, stream>>>(UB, batch, Wlin, blin, out, n_nodes);
}

// Round 7
// 345.728 us; speedup vs baseline: 1.8338x; 1.3720x over previous
//
#include <hip/hip_runtime.h>
#include <hip/hip_bf16.h>

typedef __attribute__((ext_vector_type(8))) short short8v;
typedef __attribute__((ext_vector_type(4))) float f32x4;

// Activation storage: separate hi/lo bf16 planes, stride 128 shorts (256 B).
// feats 0..99 valid, 100..127 zero pad. K-order for GEMM: part0 = aggr planes,
// part1 = x planes; 4 chunks of 32 feats per part.
#define PST 128

static __device__ inline unsigned short f2bf(float x) {
    union { float f; unsigned int u; } c; c.f = x;
    unsigned int r = (c.u + 0x7FFFu + ((c.u >> 16) & 1u)) >> 16;
    return (unsigned short)r;
}
static __device__ inline float bf2f(unsigned short h) {
    union { float f; unsigned int u; } c; c.u = ((unsigned int)h) << 16;
    return c.f;
}
static __device__ inline f32x4 MF(short8v a, short8v b, f32x4 c) {
    return __builtin_amdgcn_mfma_f32_16x16x32_bf16(a, b, c, 0, 0, 0);
}

// ---------------- CSR build ----------------

__global__ __launch_bounds__(256) void k_count(const int* __restrict__ key,
                                               int* __restrict__ cnt, int n) {
    int e = blockIdx.x * 256 + threadIdx.x;
    if (e < n) atomicAdd(&cnt[key[e]], 1);
}

__global__ __launch_bounds__(1024) void k_scan1(const int* __restrict__ cnt,
                                                int* __restrict__ rowst,
                                                int* __restrict__ bsum, int n) {
    __shared__ int tmp[1024];
    int t = threadIdx.x;
    int i = blockIdx.x * 1024 + t;
    int v = (i < n) ? cnt[i] : 0;
    tmp[t] = v;
    __syncthreads();
    for (int off = 1; off < 1024; off <<= 1) {
        int u = 0;
        if (t >= off) u = tmp[t - off];
        __syncthreads();
        if (t >= off) tmp[t] += u;
        __syncthreads();
    }
    if (i < n) rowst[i] = tmp[t] - v;
    if (t == 1023) bsum[blockIdx.x] = tmp[1023];
}

__global__ __launch_bounds__(256) void k_scan3(const int* __restrict__ cnt,
                                               int* __restrict__ rowst,
                                               const int* __restrict__ bsum,
                                               int* __restrict__ cur,
                                               float* __restrict__ inv, int n) {
    int i = blockIdx.x * 256 + threadIdx.x;
    if (i < n) {
        int nb = i >> 10;
        int base = 0;
        for (int j = 0; j < nb; ++j) base += bsum[j];
        int r = rowst[i] + base;
        rowst[i] = r;
        cur[i] = r;
        int c = cnt[i];
        inv[i] = 1.0f / (float)(c > 1 ? c : 1);
        if (i == n - 1) rowst[n] = r + c;
    }
}

__global__ __launch_bounds__(256) void k_scatter(const int* __restrict__ src,
                                                 const int* __restrict__ dst,
                                                 int* __restrict__ cur,
                                                 int* __restrict__ ssrc, int n) {
    int e = blockIdx.x * 256 + threadIdx.x;
    if (e < n) {
        int d = dst[e];
        int p = atomicAdd(&cur[d], 1);
        ssrc[p] = src[e];
    }
}

// ---------------- x (fp32) -> hi/lo planes ----------------
// 16 lanes/node, 16 nodes per 256-block; lane l<13 covers feats 8l..8l+7.
__global__ __launch_bounds__(256) void k_cvt(const float* __restrict__ X,
                                             unsigned short* __restrict__ Xhi,
                                             unsigned short* __restrict__ Xlo,
                                             int n) {
    int grp = threadIdx.x >> 4, l = threadIdx.x & 15;
    int i = blockIdx.x * 16 + grp;
    if (i >= n) return;
    unsigned short* ph = Xhi + (size_t)i * PST + l * 8;
    unsigned short* pl = Xlo + (size_t)i * PST + l * 8;
    if (l < 13) {
        float4 v0 = *(const float4*)(X + (size_t)i * 100 + l * 8);
        float4 v1 = (l < 12) ? *(const float4*)(X + (size_t)i * 100 + l * 8 + 4)
                             : make_float4(0.f, 0.f, 0.f, 0.f);
        float f[8] = {v0.x, v0.y, v0.z, v0.w, v1.x, v1.y, v1.z, v1.w};
        short8v hv, lv;
#pragma unroll
        for (int m = 0; m < 8; ++m) {
            unsigned short h = f2bf(f[m]);
            hv[m] = (short)h;
            lv[m] = (short)f2bf(f[m] - bf2f(h));
        }
        *(short8v*)ph = hv;
        *(short8v*)pl = lv;
    } else {
        short8v z = (short8v){0,0,0,0,0,0,0,0};
        *(short8v*)ph = z;
        *(short8v*)pl = z;
    }
}

// ---------------- mean aggregation over CSR (hi-only gather) ----------------
// 16 lanes/node, 16 nodes/block; lanes 0..12 each load 16B of the 208B hi row.
__global__ __launch_bounds__(256) void k_aggr(const unsigned short* __restrict__ Xhi,
                                              const int* __restrict__ ssrc,
                                              const int* __restrict__ rowst,
                                              const float* __restrict__ inv,
                                              unsigned short* __restrict__ Ahi,
                                              unsigned short* __restrict__ Alo,
                                              int n) {
    int grp = threadIdx.x >> 4;
    int l = threadIdx.x & 15;
    int node = blockIdx.x * 16 + grp;
    if (node >= n) return;
    int s = rowst[node];
    int e = rowst[node + 1];
    const bool act = l < 13;
    float a[8];
#pragma unroll
    for (int m = 0; m < 8; ++m) a[m] = 0.f;
    const size_t loff = (size_t)l * 8;

    int i = s;
    for (; i + 4 <= e; i += 4) {
        int s0 = ssrc[i], s1 = ssrc[i + 1], s2 = ssrc[i + 2], s3 = ssrc[i + 3];
        if (act) {
            short8v v0 = *(const short8v*)(Xhi + (size_t)s0 * PST + loff);
            short8v v1 = *(const short8v*)(Xhi + (size_t)s1 * PST + loff);
            short8v v2 = *(const short8v*)(Xhi + (size_t)s2 * PST + loff);
            short8v v3 = *(const short8v*)(Xhi + (size_t)s3 * PST + loff);
#pragma unroll
            for (int m = 0; m < 8; ++m)
                a[m] += bf2f((unsigned short)v0[m]) + bf2f((unsigned short)v1[m])
                      + bf2f((unsigned short)v2[m]) + bf2f((unsigned short)v3[m]);
        }
    }
    for (; i < e; ++i) {
        int s0 = ssrc[i];
        if (act) {
            short8v v0 = *(const short8v*)(Xhi + (size_t)s0 * PST + loff);
#pragma unroll
            for (int m = 0; m < 8; ++m) a[m] += bf2f((unsigned short)v0[m]);
        }
    }

    unsigned short* oh = Ahi + (size_t)node * PST + loff;
    unsigned short* ol = Alo + (size_t)node * PST + loff;
    if (act) {
        const float f = inv[node];
        short8v hv, lv;
#pragma unroll
        for (int m = 0; m < 8; ++m) {
            float v = a[m] * f;
            unsigned short h = f2bf(v);
            hv[m] = (short)h;
            lv[m] = (short)f2bf(v - bf2f(h));
        }
        *(short8v*)oh = hv;
        *(short8v*)ol = lv;
    } else {
        short8v z = (short8v){0,0,0,0,0,0,0,0};
        *(short8v*)oh = z;
        *(short8v*)ol = z;
    }
}

// ---------------- weight pack: Bh/Bl fragments ----------------
// idx = ((part*4 + c)*7 + nt)*64 + lane; feat = c*32 + (lane>>4)*8 + jj;
// col = nt*16 + (lane&15). part0 -> Wl (aggr), part1 -> Wr (root x).
__global__ __launch_bounds__(256) void k_pack(const float* __restrict__ Wl,
                                              const float* __restrict__ Wr,
                                              unsigned short* __restrict__ Bh,
                                              unsigned short* __restrict__ Bl) {
    int idx = blockIdx.x * 256 + threadIdx.x;
    if (idx >= 2 * 4 * 7 * 64) return;
    int lane = idx & 63;
    int t = idx >> 6;
    int nt = t % 7;
    int pc = t / 7;
    int part = pc >> 2, c = pc & 3;
    int col = nt * 16 + (lane & 15);
    int fbase = c * 32 + (lane >> 4) * 8;
    const float* W = part ? Wr : Wl;
    for (int jj = 0; jj < 8; ++jj) {
        int k = fbase + jj;
        float w = (k < 100 && col < 100) ? W[k * 100 + col] : 0.f;
        unsigned short h = f2bf(w);
        Bh[(size_t)idx * 8 + jj] = h;
        Bl[(size_t)idx * 8 + jj] = f2bf(w - bf2f(h));
    }
}

// ---------------- MFMA GEMM: O = act(aggr@Wl + x@Wr + b) --------------------
// 1 wave = 32 rows (2 M-tiles), N=112 (7 tiles). Per part (A,X), 4 K-chunks,
// 3-term split: hi*Whi + hi*Wlo + lo*Whi -> 336 MFMA/wave. No LDS/barriers.
__global__ __launch_bounds__(256) void k_gemm(const unsigned short* __restrict__ Ahi,
                                              const unsigned short* __restrict__ Alo,
                                              const unsigned short* __restrict__ Xhi,
                                              const unsigned short* __restrict__ Xlo,
                                              const unsigned short* __restrict__ Bh,
                                              const unsigned short* __restrict__ Bl,
                                              const float* __restrict__ bias,
                                              unsigned short* __restrict__ Ohi,
                                              unsigned short* __restrict__ Olo,
                                              int relu, int n, int ntasks) {
    const int lane = threadIdx.x & 63;
    const int wv = threadIdx.x >> 6;
    const int task = blockIdx.x * 4 + wv;
    if (task >= ntasks) return;
    const int m0 = task * 32;
    const int lrow = lane & 15;
    const int lg = lane >> 4;

    f32x4 acc[2][7];
#pragma unroll
    for (int mt = 0; mt < 2; ++mt)
#pragma unroll
        for (int nt = 0; nt < 7; ++nt) acc[mt][nt] = (f32x4){0.f, 0.f, 0.f, 0.f};

    int r0 = m0 + lrow;      if (r0 >= n) r0 = n - 1;
    int r1 = m0 + 16 + lrow; if (r1 >= n) r1 = n - 1;
    const size_t b0 = (size_t)r0 * PST + lg * 8;
    const size_t b1 = (size_t)r1 * PST + lg * 8;
    const unsigned short* ph[2] = {Ahi, Xhi};
    const unsigned short* pl[2] = {Alo, Xlo};

#pragma unroll
    for (int part = 0; part < 2; ++part) {
#pragma unroll
        for (int c = 0; c < 4; ++c) {
            short8v ah0 = *(const short8v*)(ph[part] + b0 + c * 32);
            short8v al0 = *(const short8v*)(pl[part] + b0 + c * 32);
            short8v ah1 = *(const short8v*)(ph[part] + b1 + c * 32);
            short8v al1 = *(const short8v*)(pl[part] + b1 + c * 32);
            const unsigned short* bph = Bh + ((size_t)((part * 4 + c) * 7) * 64 + lane) * 8;
            const unsigned short* bpl = Bl + ((size_t)((part * 4 + c) * 7) * 64 + lane) * 8;
#pragma unroll
            for (int nt = 0; nt < 7; ++nt) {
                short8v bh = *(const short8v*)(bph + nt * 512);
                short8v bl = *(const short8v*)(bpl + nt * 512);
                acc[0][nt] = MF(ah0, bh, acc[0][nt]);
                acc[0][nt] = MF(ah0, bl, acc[0][nt]);
                acc[0][nt] = MF(al0, bh, acc[0][nt]);
                acc[1][nt] = MF(ah1, bh, acc[1][nt]);
                acc[1][nt] = MF(ah1, bl, acc[1][nt]);
                acc[1][nt] = MF(al1, bh, acc[1][nt]);
            }
        }
    }

    // epilogue: C/D layout col=lane&15, row=(lane>>4)*4+reg  [HW-verified]
#pragma unroll
    for (int nt = 0; nt < 7; ++nt) {
        int col = nt * 16 + lrow;
        bool cok = col < 100;
        float bb = cok ? bias[col] : 0.f;
#pragma unroll
        for (int mt = 0; mt < 2; ++mt) {
#pragma unroll
            for (int r = 0; r < 4; ++r) {
                int row = m0 + mt * 16 + lg * 4 + r;
                if (cok && row < n) {
                    float v = acc[mt][nt][r] + bb;
                    if (relu) v = fmaxf(v, 0.f);
                    unsigned short h = f2bf(v);
                    size_t o = (size_t)row * PST + col;
                    Ohi[o] = h;
                    Olo[o] = f2bf(v - bf2f(h));
                }
            }
        }
    }
    // zero pad cols 100..127 (56B at byte offset row*256+200 per plane)
    {
        int row = m0 + (lane >> 1);
        if (row < n) {
            unsigned short* op = ((lane & 1) == 0 ? Ohi : Olo) + (size_t)row * PST;
            short4 z4 = {0, 0, 0, 0};
            short8v z = (short8v){0,0,0,0,0,0,0,0};
            *(short4*)(op + 100) = z4;
            *(short8v*)(op + 104) = z;
            *(short8v*)(op + 112) = z;
            *(short8v*)(op + 120) = z;
        }
    }
}

// ---------------- pool + head: 1 block/graph ----------------
// 16 lane-groups stride the node range; lane l<13 covers feats 8l..8l+7
// (hi+lo planes); plain-store LDS tree reduce; fused head.
__global__ __launch_bounds__(256) void k_pool(const unsigned short* __restrict__ Hhi,
                                              const unsigned short* __restrict__ Hlo,
                                              const int* __restrict__ batch,
                                              const float* __restrict__ Wlin,
                                              const float* __restrict__ blin,
                                              float* __restrict__ out, int n) {
    int g = blockIdx.x;
    int t = threadIdx.x;
    int grp = t >> 4, l = t & 15;
    int lo = 0, hi = n;
    while (lo < hi) { int m = (lo + hi) >> 1; if (batch[m] < g) lo = m + 1; else hi = m; }
    int lo2 = lo, hi2 = n;
    while (lo2 < hi2) { int m = (lo2 + hi2) >> 1; if (batch[m] < g + 1) lo2 = m + 1; else hi2 = m; }

    const bool act = l < 13;
    float a[8];
#pragma unroll
    for (int m = 0; m < 8; ++m) a[m] = 0.f;
    const size_t loff = (size_t)l * 8;
    for (int node = lo + grp; node < lo2; node += 16) {
        if (act) {
            short8v vh = *(const short8v*)(Hhi + (size_t)node * PST + loff);
            short8v vl = *(const short8v*)(Hlo + (size_t)node * PST + loff);
#pragma unroll
            for (int m = 0; m < 8; ++m)
                a[m] += bf2f((unsigned short)vh[m]) + bf2f((unsigned short)vl[m]);
        }
    }

    __shared__ float part[16][13][8];
    if (act) {
#pragma unroll
        for (int m = 0; m < 8; ++m) part[grp][l][m] = a[m];
    }
    __syncthreads();

    __shared__ float gm[104];
    if (t < 104) {
        int fg = t >> 3, m = t & 7;
        float s = 0.f;
#pragma unroll
        for (int q = 0; q < 16; ++q) s += part[q][fg][m];
        float f = (lo2 > lo) ? 1.0f / (float)(lo2 - lo) : 0.0f;
        gm[t] = s * f;
    }
    __syncthreads();
    if (t < 2) {
        float o = blin[t];
        for (int k = 0; k < 100; ++k) o += gm[k] * Wlin[k * 2 + t];
        out[g * 2 + t] = o;
    }
}

// ---------------- launch ----------------

extern "C" void kernel_launch(void* const* d_in, const int* in_sizes, int n_in,
                              void* d_out, int out_size, void* d_ws, size_t ws_size,
                              hipStream_t stream) {
    const float* x    = (const float*)d_in[0];
    const int*   ei   = (const int*)d_in[1];
    const int*   batch= (const int*)d_in[2];
    const float* W1l  = (const float*)d_in[3];
    const float* b1   = (const float*)d_in[4];
    const float* W1r  = (const float*)d_in[5];
    const float* W2l  = (const float*)d_in[6];
    const float* b2   = (const float*)d_in[7];
    const float* W2r  = (const float*)d_in[8];
    const float* W3l  = (const float*)d_in[9];
    const float* b3   = (const float*)d_in[10];
    const float* W3r  = (const float*)d_in[11];
    const float* Wlin = (const float*)d_in[12];
    const float* blin = (const float*)d_in[13];
    float* out = (float*)d_out;

    const int n_nodes  = in_sizes[0] / 100;
    const int n_edges  = in_sizes[1] / 2;
    const int n_graphs = out_size / 2;
    const int* src = ei;
    const int* dst = ei + n_edges;

    char* ws = (char*)d_ws;
    size_t o = 0;
    auto alloc = [&](size_t bytes) { size_t r = o; o = (o + bytes + 255) & ~(size_t)255; return r; };
    int*   cnt  = (int*)(ws + alloc((size_t)n_nodes * 4));
    int*   rowp = (int*)(ws + alloc((size_t)(n_nodes + 1) * 4));
    int*   cur  = (int*)(ws + alloc((size_t)n_nodes * 4));
    int*   bsum = (int*)(ws + alloc(64 * 4));
    float* inv  = (float*)(ws + alloc((size_t)n_nodes * 4));
    int*   ssrc = (int*)(ws + alloc((size_t)n_edges * 4));
    const size_t pbytes = (size_t)n_nodes * PST * 2;  // one bf16 plane
    unsigned short* XAhi = (unsigned short*)(ws + alloc(pbytes));
    unsigned short* XAlo = (unsigned short*)(ws + alloc(pbytes));
    unsigned short* XBhi = (unsigned short*)(ws + alloc(pbytes));
    unsigned short* XBlo = (unsigned short*)(ws + alloc(pbytes));
    unsigned short* AGhi = (unsigned short*)(ws + alloc(pbytes));
    unsigned short* AGlo = (unsigned short*)(ws + alloc(pbytes));
    const size_t bfb = (size_t)2 * 4 * 7 * 64 * 8 * 2;  // 57344 B per plane
    unsigned short* B1h = (unsigned short*)(ws + alloc(bfb));
    unsigned short* B1l = (unsigned short*)(ws + alloc(bfb));
    unsigned short* B2h = (unsigned short*)(ws + alloc(bfb));
    unsigned short* B2l = (unsigned short*)(ws + alloc(bfb));
    unsigned short* B3h = (unsigned short*)(ws + alloc(bfb));
    unsigned short* B3l = (unsigned short*)(ws + alloc(bfb));

    hipMemsetAsync(cnt, 0, (size_t)n_nodes * 4, stream);

    const int eb = (n_edges + 255) / 256;
    const int sb = (n_nodes + 1023) / 1024;
    const int nb256 = (n_nodes + 255) / 256;

    k_count<<<eb, 256, 0, stream>>>(dst, cnt, n_edges);
    k_scan1<<<sb, 1024, 0, stream>>>(cnt, rowp, bsum, n_nodes);
    k_scan3<<<nb256, 256, 0, stream>>>(cnt, rowp, bsum, cur, inv, n_nodes);
    k_scatter<<<eb, 256, 0, stream>>>(src, dst, cur, ssrc, n_edges);

    const int pkb = (2 * 4 * 7 * 64 + 255) / 256;
    k_pack<<<pkb, 256, 0, stream>>>(W1l, W1r, B1h, B1l);
    k_pack<<<pkb, 256, 0, stream>>>(W2l, W2r, B2h, B2l);
    k_pack<<<pkb, 256, 0, stream>>>(W3l, W3r, B3h, B3l);

    const int nb16 = (n_nodes + 15) / 16;
    const int ntasks = (n_nodes + 31) / 32;
    const int ggrid = (ntasks + 3) / 4;

    k_cvt<<<nb16, 256, 0, stream>>>(x, XAhi, XAlo, n_nodes);

    // layer 1
    k_aggr<<<nb16, 256, 0, stream>>>(XAhi, ssrc, rowp, inv, AGhi, AGlo, n_nodes);
    k_gemm<<<ggrid, 256, 0, stream>>>(AGhi, AGlo, XAhi, XAlo, B1h, B1l, b1,
                                      XBhi, XBlo, 1, n_nodes, ntasks);
    // layer 2
    k_aggr<<<nb16, 256, 0, stream>>>(XBhi, ssrc, rowp, inv, AGhi, AGlo, n_nodes);
    k_gemm<<<ggrid, 256, 0, stream>>>(AGhi, AGlo, XBhi, XBlo, B2h, B2l, b2,
                                      XAhi, XAlo, 1, n_nodes, ntasks);
    // layer 3 (no relu)
    k_aggr<<<nb16, 256, 0, stream>>>(XAhi, ssrc, rowp, inv, AGhi, AGlo, n_nodes);
    k_gemm<<<ggrid, 256, 0, stream>>>(AGhi, AGlo, XAhi, XAlo, B3h, B3l, b3,
                                      XBhi, XBlo, 0, n_nodes, ntasks);

    k_pool<<<n_graphs, 256, 0, stream>>>(XBhi, XBlo, batch, Wlin, blin, out, n_nodes);
}

// Round 8
// 337.648 us; speedup vs baseline: 1.8777x; 1.0239x over previous
//
#include <hip/hip_runtime.h>
#include <hip/hip_bf16.h>

typedef __attribute__((ext_vector_type(8))) short short8v;
typedef __attribute__((ext_vector_type(4))) float f32x4;

// Activation storage: separate hi/lo bf16 planes, stride 128 shorts (256 B).
// feats 0..99 valid, 100..127 zero pad.
#define PST 128
#define MAXBUCK 1024

static __device__ inline unsigned short f2bf(float x) {
    union { float f; unsigned int u; } c; c.f = x;
    unsigned int r = (c.u + 0x7FFFu + ((c.u >> 16) & 1u)) >> 16;
    return (unsigned short)r;
}
static __device__ inline float bf2f(unsigned short h) {
    union { float f; unsigned int u; } c; c.u = ((unsigned int)h) << 16;
    return c.f;
}
static __device__ inline f32x4 MF(short8v a, short8v b, f32x4 c) {
    return __builtin_amdgcn_mfma_f32_16x16x32_bf16(a, b, c, 0, 0, 0);
}

// ---------------- CSR build ----------------

__global__ __launch_bounds__(256) void k_count(const int* __restrict__ key,
                                               int* __restrict__ cnt, int n) {
    int e = blockIdx.x * 256 + threadIdx.x;
    if (e < n) atomicAdd(&cnt[key[e]], 1);
}

__global__ __launch_bounds__(1024) void k_scan1(const int* __restrict__ cnt,
                                                int* __restrict__ rowst,
                                                int* __restrict__ bsum, int n) {
    __shared__ int tmp[1024];
    int t = threadIdx.x;
    int i = blockIdx.x * 1024 + t;
    int v = (i < n) ? cnt[i] : 0;
    tmp[t] = v;
    __syncthreads();
    for (int off = 1; off < 1024; off <<= 1) {
        int u = 0;
        if (t >= off) u = tmp[t - off];
        __syncthreads();
        if (t >= off) tmp[t] += u;
        __syncthreads();
    }
    if (i < n) rowst[i] = tmp[t] - v;
    if (t == 1023) bsum[blockIdx.x] = tmp[1023];
}

__global__ __launch_bounds__(256) void k_scan3(const int* __restrict__ cnt,
                                               int* __restrict__ rowst,
                                               const int* __restrict__ bsum,
                                               int* __restrict__ cur,
                                               float* __restrict__ inv, int n) {
    int i = blockIdx.x * 256 + threadIdx.x;
    if (i < n) {
        int nb = i >> 10;
        int base = 0;
        for (int j = 0; j < nb; ++j) base += bsum[j];
        int r = rowst[i] + base;
        rowst[i] = r;
        cur[i] = r;
        int c = cnt[i];
        inv[i] = 1.0f / (float)(c > 1 ? c : 1);
        if (i == n - 1) rowst[n] = r + c;
    }
}

// ---- binned edge sort (bucket = dst>>8) for XCD/line-local final scatter ----

__global__ __launch_bounds__(256) void k_bincount(const int* __restrict__ dst,
                                                  int* __restrict__ bcnt,
                                                  int n, int nbuck, int chunk) {
    __shared__ int lcnt[MAXBUCK];
    int t = threadIdx.x;
    for (int b = t; b < nbuck; b += 256) lcnt[b] = 0;
    __syncthreads();
    int e0 = blockIdx.x * chunk;
    int e1 = e0 + chunk; if (e1 > n) e1 = n;
    for (int e = e0 + t; e < e1; e += 256) atomicAdd(&lcnt[dst[e] >> 8], 1);
    __syncthreads();
    for (int b = t; b < nbuck; b += 256)
        if (lcnt[b]) atomicAdd(&bcnt[b], lcnt[b]);
}

__global__ __launch_bounds__(1024) void k_binscan(const int* __restrict__ bcnt,
                                                  int* __restrict__ bbase,
                                                  int* __restrict__ bcur, int nbuck) {
    __shared__ int tmp[1024];
    int t = threadIdx.x;
    int v = (t < nbuck) ? bcnt[t] : 0;
    tmp[t] = v;
    __syncthreads();
    for (int off = 1; off < 1024; off <<= 1) {
        int u = 0;
        if (t >= off) u = tmp[t - off];
        __syncthreads();
        if (t >= off) tmp[t] += u;
        __syncthreads();
    }
    if (t < nbuck) { int b = tmp[t] - v; bbase[t] = b; bcur[t] = b; }
}

__global__ __launch_bounds__(256) void k_binscatter(const int* __restrict__ src,
                                                    const int* __restrict__ dst,
                                                    int* __restrict__ bcur,
                                                    int2* __restrict__ tmpv,
                                                    int n, int nbuck, int chunk) {
    __shared__ int lcnt[MAXBUCK];
    __shared__ int lbase[MAXBUCK];
    int t = threadIdx.x;
    for (int b = t; b < nbuck; b += 256) lcnt[b] = 0;
    __syncthreads();
    int e0 = blockIdx.x * chunk;
    int e1 = e0 + chunk; if (e1 > n) e1 = n;
    for (int e = e0 + t; e < e1; e += 256) atomicAdd(&lcnt[dst[e] >> 8], 1);
    __syncthreads();
    for (int b = t; b < nbuck; b += 256) {
        int c = lcnt[b];
        lbase[b] = c ? atomicAdd(&bcur[b], c) : 0;
        lcnt[b] = 0;  // reuse as local cursor
    }
    __syncthreads();
    for (int e = e0 + t; e < e1; e += 256) {
        int d = dst[e];
        int b = d >> 8;
        int r = atomicAdd(&lcnt[b], 1);
        tmpv[lbase[b] + r] = make_int2(src[e], d);
    }
}

// one block per bucket: all cur[]/ssrc traffic confined to this bucket's range
__global__ __launch_bounds__(256) void k_scatter2(const int2* __restrict__ tmpv,
                                                  const int* __restrict__ bbase,
                                                  const int* __restrict__ bcnt,
                                                  int* __restrict__ cur,
                                                  int* __restrict__ ssrc, int nbuck) {
    int b = blockIdx.x;
    int s = bbase[b], e = s + bcnt[b];
    for (int i = s + threadIdx.x; i < e; i += 256) {
        int2 p = tmpv[i];
        int pos = atomicAdd(&cur[p.y], 1);
        ssrc[pos] = p.x;
    }
}

// ---------------- x (fp32) -> hi/lo planes ----------------
__global__ __launch_bounds__(256) void k_cvt(const float* __restrict__ X,
                                             unsigned short* __restrict__ Xhi,
                                             unsigned short* __restrict__ Xlo,
                                             int n) {
    int grp = threadIdx.x >> 4, l = threadIdx.x & 15;
    int i = blockIdx.x * 16 + grp;
    if (i >= n) return;
    unsigned short* ph = Xhi + (size_t)i * PST + l * 8;
    unsigned short* pl = Xlo + (size_t)i * PST + l * 8;
    if (l < 13) {
        float4 v0 = *(const float4*)(X + (size_t)i * 100 + l * 8);
        float4 v1 = (l < 12) ? *(const float4*)(X + (size_t)i * 100 + l * 8 + 4)
                             : make_float4(0.f, 0.f, 0.f, 0.f);
        float f[8] = {v0.x, v0.y, v0.z, v0.w, v1.x, v1.y, v1.z, v1.w};
        short8v hv, lv;
#pragma unroll
        for (int m = 0; m < 8; ++m) {
            unsigned short h = f2bf(f[m]);
            hv[m] = (short)h;
            lv[m] = (short)f2bf(f[m] - bf2f(h));
        }
        *(short8v*)ph = hv;
        *(short8v*)pl = lv;
    } else {
        short8v z = (short8v){0,0,0,0,0,0,0,0};
        *(short8v*)ph = z;
        *(short8v*)pl = z;
    }
}

// ---------------- mean aggregation over CSR (hi-only gather) ----------------
__global__ __launch_bounds__(256) void k_aggr(const unsigned short* __restrict__ Xhi,
                                              const int* __restrict__ ssrc,
                                              const int* __restrict__ rowst,
                                              const float* __restrict__ inv,
                                              unsigned short* __restrict__ Ahi,
                                              unsigned short* __restrict__ Alo,
                                              int n) {
    int grp = threadIdx.x >> 4;
    int l = threadIdx.x & 15;
    int node = blockIdx.x * 16 + grp;
    if (node >= n) return;
    int s = rowst[node];
    int e = rowst[node + 1];
    const bool act = l < 13;
    float a[8];
#pragma unroll
    for (int m = 0; m < 8; ++m) a[m] = 0.f;
    const size_t loff = (size_t)l * 8;

    int i = s;
    for (; i + 4 <= e; i += 4) {
        int s0 = ssrc[i], s1 = ssrc[i + 1], s2 = ssrc[i + 2], s3 = ssrc[i + 3];
        if (act) {
            short8v v0 = *(const short8v*)(Xhi + (size_t)s0 * PST + loff);
            short8v v1 = *(const short8v*)(Xhi + (size_t)s1 * PST + loff);
            short8v v2 = *(const short8v*)(Xhi + (size_t)s2 * PST + loff);
            short8v v3 = *(const short8v*)(Xhi + (size_t)s3 * PST + loff);
#pragma unroll
            for (int m = 0; m < 8; ++m)
                a[m] += bf2f((unsigned short)v0[m]) + bf2f((unsigned short)v1[m])
                      + bf2f((unsigned short)v2[m]) + bf2f((unsigned short)v3[m]);
        }
    }
    for (; i < e; ++i) {
        int s0 = ssrc[i];
        if (act) {
            short8v v0 = *(const short8v*)(Xhi + (size_t)s0 * PST + loff);
#pragma unroll
            for (int m = 0; m < 8; ++m) a[m] += bf2f((unsigned short)v0[m]);
        }
    }

    unsigned short* oh = Ahi + (size_t)node * PST + loff;
    unsigned short* ol = Alo + (size_t)node * PST + loff;
    if (act) {
        const float f = inv[node];
        short8v hv, lv;
#pragma unroll
        for (int m = 0; m < 8; ++m) {
            float v = a[m] * f;
            unsigned short h = f2bf(v);
            hv[m] = (short)h;
            lv[m] = (short)f2bf(v - bf2f(h));
        }
        *(short8v*)oh = hv;
        *(short8v*)ol = lv;
    } else {
        short8v z = (short8v){0,0,0,0,0,0,0,0};
        *(short8v*)oh = z;
        *(short8v*)ol = z;
    }
}

// ---------------- weight pack ----------------
__global__ __launch_bounds__(256) void k_pack(const float* __restrict__ Wl,
                                              const float* __restrict__ Wr,
                                              unsigned short* __restrict__ Bh,
                                              unsigned short* __restrict__ Bl) {
    int idx = blockIdx.x * 256 + threadIdx.x;
    if (idx >= 2 * 4 * 7 * 64) return;
    int lane = idx & 63;
    int t = idx >> 6;
    int nt = t % 7;
    int pc = t / 7;
    int part = pc >> 2, c = pc & 3;
    int col = nt * 16 + (lane & 15);
    int fbase = c * 32 + (lane >> 4) * 8;
    const float* W = part ? Wr : Wl;
    for (int jj = 0; jj < 8; ++jj) {
        int k = fbase + jj;
        float w = (k < 100 && col < 100) ? W[k * 100 + col] : 0.f;
        unsigned short h = f2bf(w);
        Bh[(size_t)idx * 8 + jj] = h;
        Bl[(size_t)idx * 8 + jj] = f2bf(w - bf2f(h));
    }
}

// ---------------- MFMA GEMM: O = act(aggr@Wl + x@Wr + b) --------------------
__global__ __launch_bounds__(256) void k_gemm(const unsigned short* __restrict__ Ahi,
                                              const unsigned short* __restrict__ Alo,
                                              const unsigned short* __restrict__ Xhi,
                                              const unsigned short* __restrict__ Xlo,
                                              const unsigned short* __restrict__ Bh,
                                              const unsigned short* __restrict__ Bl,
                                              const float* __restrict__ bias,
                                              unsigned short* __restrict__ Ohi,
                                              unsigned short* __restrict__ Olo,
                                              int relu, int n, int ntasks) {
    const int lane = threadIdx.x & 63;
    const int wv = threadIdx.x >> 6;
    const int task = blockIdx.x * 4 + wv;
    if (task >= ntasks) return;
    const int m0 = task * 32;
    const int lrow = lane & 15;
    const int lg = lane >> 4;

    f32x4 acc[2][7];
#pragma unroll
    for (int mt = 0; mt < 2; ++mt)
#pragma unroll
        for (int nt = 0; nt < 7; ++nt) acc[mt][nt] = (f32x4){0.f, 0.f, 0.f, 0.f};

    int r0 = m0 + lrow;      if (r0 >= n) r0 = n - 1;
    int r1 = m0 + 16 + lrow; if (r1 >= n) r1 = n - 1;
    const size_t b0 = (size_t)r0 * PST + lg * 8;
    const size_t b1 = (size_t)r1 * PST + lg * 8;
    const unsigned short* ph[2] = {Ahi, Xhi};
    const unsigned short* pl[2] = {Alo, Xlo};

#pragma unroll
    for (int part = 0; part < 2; ++part) {
#pragma unroll
        for (int c = 0; c < 4; ++c) {
            short8v ah0 = *(const short8v*)(ph[part] + b0 + c * 32);
            short8v al0 = *(const short8v*)(pl[part] + b0 + c * 32);
            short8v ah1 = *(const short8v*)(ph[part] + b1 + c * 32);
            short8v al1 = *(const short8v*)(pl[part] + b1 + c * 32);
            const unsigned short* bph = Bh + ((size_t)((part * 4 + c) * 7) * 64 + lane) * 8;
            const unsigned short* bpl = Bl + ((size_t)((part * 4 + c) * 7) * 64 + lane) * 8;
#pragma unroll
            for (int nt = 0; nt < 7; ++nt) {
                short8v bh = *(const short8v*)(bph + nt * 512);
                short8v bl = *(const short8v*)(bpl + nt * 512);
                acc[0][nt] = MF(ah0, bh, acc[0][nt]);
                acc[0][nt] = MF(ah0, bl, acc[0][nt]);
                acc[0][nt] = MF(al0, bh, acc[0][nt]);
                acc[1][nt] = MF(ah1, bh, acc[1][nt]);
                acc[1][nt] = MF(ah1, bl, acc[1][nt]);
                acc[1][nt] = MF(al1, bh, acc[1][nt]);
            }
        }
    }

    // epilogue: C/D layout col=lane&15, row=(lane>>4)*4+reg  [HW-verified]
#pragma unroll
    for (int nt = 0; nt < 7; ++nt) {
        int col = nt * 16 + lrow;
        bool cok = col < 100;
        float bb = cok ? bias[col] : 0.f;
#pragma unroll
        for (int mt = 0; mt < 2; ++mt) {
#pragma unroll
            for (int r = 0; r < 4; ++r) {
                int row = m0 + mt * 16 + lg * 4 + r;
                if (cok && row < n) {
                    float v = acc[mt][nt][r] + bb;
                    if (relu) v = fmaxf(v, 0.f);
                    unsigned short h = f2bf(v);
                    size_t o = (size_t)row * PST + col;
                    Ohi[o] = h;
                    Olo[o] = f2bf(v - bf2f(h));
                }
            }
        }
    }
    // zero pad cols 100..127
    {
        int row = m0 + (lane >> 1);
        if (row < n) {
            unsigned short* op = ((lane & 1) == 0 ? Ohi : Olo) + (size_t)row * PST;
            short4 z4 = {0, 0, 0, 0};
            short8v z = (short8v){0,0,0,0,0,0,0,0};
            *(short4*)(op + 100) = z4;
            *(short8v*)(op + 104) = z;
            *(short8v*)(op + 112) = z;
            *(short8v*)(op + 120) = z;
        }
    }
}

// ---------------- pool + head: 1 block/graph ----------------
__global__ __launch_bounds__(256) void k_pool(const unsigned short* __restrict__ Hhi,
                                              const unsigned short* __restrict__ Hlo,
                                              const int* __restrict__ batch,
                                              const float* __restrict__ Wlin,
                                              const float* __restrict__ blin,
                                              float* __restrict__ out, int n) {
    int g = blockIdx.x;
    int t = threadIdx.x;
    int grp = t >> 4, l = t & 15;
    int lo = 0, hi = n;
    while (lo < hi) { int m = (lo + hi) >> 1; if (batch[m] < g) lo = m + 1; else hi = m; }
    int lo2 = lo, hi2 = n;
    while (lo2 < hi2) { int m = (lo2 + hi2) >> 1; if (batch[m] < g + 1) lo2 = m + 1; else hi2 = m; }

    const bool act = l < 13;
    float a[8];
#pragma unroll
    for (int m = 0; m < 8; ++m) a[m] = 0.f;
    const size_t loff = (size_t)l * 8;
    for (int node = lo + grp; node < lo2; node += 16) {
        if (act) {
            short8v vh = *(const short8v*)(Hhi + (size_t)node * PST + loff);
            short8v vl = *(const short8v*)(Hlo + (size_t)node * PST + loff);
#pragma unroll
            for (int m = 0; m < 8; ++m)
                a[m] += bf2f((unsigned short)vh[m]) + bf2f((unsigned short)vl[m]);
        }
    }

    __shared__ float part[16][13][8];
    if (act) {
#pragma unroll
        for (int m = 0; m < 8; ++m) part[grp][l][m] = a[m];
    }
    __syncthreads();

    __shared__ float gm[104];
    if (t < 104) {
        int fg = t >> 3, m = t & 7;
        float s = 0.f;
#pragma unroll
        for (int q = 0; q < 16; ++q) s += part[q][fg][m];
        float f = (lo2 > lo) ? 1.0f / (float)(lo2 - lo) : 0.0f;
        gm[t] = s * f;
    }
    __syncthreads();
    if (t < 2) {
        float o = blin[t];
        for (int k = 0; k < 100; ++k) o += gm[k] * Wlin[k * 2 + t];
        out[g * 2 + t] = o;
    }
}

// ---------------- launch ----------------

extern "C" void kernel_launch(void* const* d_in, const int* in_sizes, int n_in,
                              void* d_out, int out_size, void* d_ws, size_t ws_size,
                              hipStream_t stream) {
    const float* x    = (const float*)d_in[0];
    const int*   ei   = (const int*)d_in[1];
    const int*   batch= (const int*)d_in[2];
    const float* W1l  = (const float*)d_in[3];
    const float* b1   = (const float*)d_in[4];
    const float* W1r  = (const float*)d_in[5];
    const float* W2l  = (const float*)d_in[6];
    const float* b2   = (const float*)d_in[7];
    const float* W2r  = (const float*)d_in[8];
    const float* W3l  = (const float*)d_in[9];
    const float* b3   = (const float*)d_in[10];
    const float* W3r  = (const float*)d_in[11];
    const float* Wlin = (const float*)d_in[12];
    const float* blin = (const float*)d_in[13];
    float* out = (float*)d_out;

    const int n_nodes  = in_sizes[0] / 100;
    const int n_edges  = in_sizes[1] / 2;
    const int n_graphs = out_size / 2;
    const int* src = ei;
    const int* dst = ei + n_edges;

    char* ws = (char*)d_ws;
    size_t o = 0;
    auto alloc = [&](size_t bytes) { size_t r = o; o = (o + bytes + 255) & ~(size_t)255; return r; };
    int*   cnt  = (int*)(ws + alloc((size_t)n_nodes * 4));
    int*   rowp = (int*)(ws + alloc((size_t)(n_nodes + 1) * 4));
    int*   cur  = (int*)(ws + alloc((size_t)n_nodes * 4));
    int*   bsum = (int*)(ws + alloc(64 * 4));
    float* inv  = (float*)(ws + alloc((size_t)n_nodes * 4));
    int*   ssrc = (int*)(ws + alloc((size_t)n_edges * 4));
    int*   bcnt = (int*)(ws + alloc(MAXBUCK * 4));
    int*   bbase= (int*)(ws + alloc(MAXBUCK * 4));
    int*   bcur = (int*)(ws + alloc(MAXBUCK * 4));
    int2*  tmpv = (int2*)(ws + alloc((size_t)n_edges * 8));
    const size_t pbytes = (size_t)n_nodes * PST * 2;  // one bf16 plane
    unsigned short* XAhi = (unsigned short*)(ws + alloc(pbytes));
    unsigned short* XAlo = (unsigned short*)(ws + alloc(pbytes));
    unsigned short* XBhi = (unsigned short*)(ws + alloc(pbytes));
    unsigned short* XBlo = (unsigned short*)(ws + alloc(pbytes));
    unsigned short* AGhi = (unsigned short*)(ws + alloc(pbytes));
    unsigned short* AGlo = (unsigned short*)(ws + alloc(pbytes));
    const size_t bfb = (size_t)2 * 4 * 7 * 64 * 8 * 2;
    unsigned short* B1h = (unsigned short*)(ws + alloc(bfb));
    unsigned short* B1l = (unsigned short*)(ws + alloc(bfb));
    unsigned short* B2h = (unsigned short*)(ws + alloc(bfb));
    unsigned short* B2l = (unsigned short*)(ws + alloc(bfb));
    unsigned short* B3h = (unsigned short*)(ws + alloc(bfb));
    unsigned short* B3l = (unsigned short*)(ws + alloc(bfb));

    hipMemsetAsync(cnt, 0, (size_t)n_nodes * 4, stream);
    hipMemsetAsync(bcnt, 0, MAXBUCK * 4, stream);

    const int eb = (n_edges + 255) / 256;
    const int sb = (n_nodes + 1023) / 1024;
    const int nb256 = (n_nodes + 255) / 256;
    const int nbuck = (n_nodes + 255) >> 8;
    const int chunk = (n_edges + 255) / 256;

    // node-level CSR offsets
    k_count<<<eb, 256, 0, stream>>>(dst, cnt, n_edges);
    k_scan1<<<sb, 1024, 0, stream>>>(cnt, rowp, bsum, n_nodes);
    k_scan3<<<nb256, 256, 0, stream>>>(cnt, rowp, bsum, cur, inv, n_nodes);
    // bucket the edges, then XCD-local final scatter
    k_bincount<<<256, 256, 0, stream>>>(dst, bcnt, n_edges, nbuck, chunk);
    k_binscan<<<1, 1024, 0, stream>>>(bcnt, bbase, bcur, nbuck);
    k_binscatter<<<256, 256, 0, stream>>>(src, dst, bcur, tmpv, n_edges, nbuck, chunk);
    k_scatter2<<<nbuck, 256, 0, stream>>>(tmpv, bbase, bcnt, cur, ssrc, nbuck);

    const int pkb = (2 * 4 * 7 * 64 + 255) / 256;
    k_pack<<<pkb, 256, 0, stream>>>(W1l, W1r, B1h, B1l);
    k_pack<<<pkb, 256, 0, stream>>>(W2l, W2r, B2h, B2l);
    k_pack<<<pkb, 256, 0, stream>>>(W3l, W3r, B3h, B3l);

    const int nb16 = (n_nodes + 15) / 16;
    const int ntasks = (n_nodes + 31) / 32;
    const int ggrid = (ntasks + 3) / 4;

    k_cvt<<<nb16, 256, 0, stream>>>(x, XAhi, XAlo, n_nodes);

    // layer 1
    k_aggr<<<nb16, 256, 0, stream>>>(XAhi, ssrc, rowp, inv, AGhi, AGlo, n_nodes);
    k_gemm<<<ggrid, 256, 0, stream>>>(AGhi, AGlo, XAhi, XAlo, B1h, B1l, b1,
                                      XBhi, XBlo, 1, n_nodes, ntasks);
    // layer 2
    k_aggr<<<nb16, 256, 0, stream>>>(XBhi, ssrc, rowp, inv, AGhi, AGlo, n_nodes);
    k_gemm<<<ggrid, 256, 0, stream>>>(AGhi, AGlo, XBhi, XBlo, B2h, B2l, b2,
                                      XAhi, XAlo, 1, n_nodes, ntasks);
    // layer 3 (no relu)
    k_aggr<<<nb16, 256, 0, stream>>>(XAhi, ssrc, rowp, inv, AGhi, AGlo, n_nodes);
    k_gemm<<<ggrid, 256, 0, stream>>>(AGhi, AGlo, XAhi, XAlo, B3h, B3l, b3,
                                      XBhi, XBlo, 0, n_nodes, ntasks);

    k_pool<<<n_graphs, 256, 0, stream>>>(XBhi, XBlo, batch, Wlin, blin, out, n_nodes);
}

// Round 9
// 296.246 us; speedup vs baseline: 2.1401x; 1.1398x over previous
//
#include <hip/hip_runtime.h>
#include <hip/hip_bf16.h>

typedef __attribute__((ext_vector_type(8))) short short8v;
typedef __attribute__((ext_vector_type(4))) float f32x4;

// Activation storage: separate hi/lo bf16 planes, stride 128 shorts (256 B).
// feats 0..99 valid, 100..127 zero pad.
#define PST 128
#define MAXBUCK 1024

static __device__ inline unsigned short f2bf(float x) {
    union { float f; unsigned int u; } c; c.f = x;
    unsigned int r = (c.u + 0x7FFFu + ((c.u >> 16) & 1u)) >> 16;
    return (unsigned short)r;
}
static __device__ inline float bf2f(unsigned short h) {
    union { float f; unsigned int u; } c; c.u = ((unsigned int)h) << 16;
    return c.f;
}
static __device__ inline f32x4 MF(short8v a, short8v b, f32x4 c) {
    return __builtin_amdgcn_mfma_f32_16x16x32_bf16(a, b, c, 0, 0, 0);
}

// ---------------- CSR build ----------------

__global__ __launch_bounds__(256) void k_count(const int* __restrict__ key,
                                               int* __restrict__ cnt, int n) {
    int e = blockIdx.x * 256 + threadIdx.x;
    if (e < n) atomicAdd(&cnt[key[e]], 1);
}

__global__ __launch_bounds__(1024) void k_scan1(const int* __restrict__ cnt,
                                                int* __restrict__ rowst,
                                                int* __restrict__ bsum, int n) {
    __shared__ int tmp[1024];
    int t = threadIdx.x;
    int i = blockIdx.x * 1024 + t;
    int v = (i < n) ? cnt[i] : 0;
    tmp[t] = v;
    __syncthreads();
    for (int off = 1; off < 1024; off <<= 1) {
        int u = 0;
        if (t >= off) u = tmp[t - off];
        __syncthreads();
        if (t >= off) tmp[t] += u;
        __syncthreads();
    }
    if (i < n) rowst[i] = tmp[t] - v;
    if (t == 1023) bsum[blockIdx.x] = tmp[1023];
}

// fold cross-block prefix; build cur/inv; seed bucket cursors bcur[b]=rowp[b<<8]
__global__ __launch_bounds__(256) void k_scan3(const int* __restrict__ cnt,
                                               int* __restrict__ rowst,
                                               const int* __restrict__ bsum,
                                               int* __restrict__ cur,
                                               int* __restrict__ bcur,
                                               float* __restrict__ inv, int n) {
    int i = blockIdx.x * 256 + threadIdx.x;
    if (i < n) {
        int nb = i >> 10;
        int base = 0;
        for (int j = 0; j < nb; ++j) base += bsum[j];
        int r = rowst[i] + base;
        rowst[i] = r;
        cur[i] = r;
        if ((i & 255) == 0) bcur[i >> 8] = r;
        int c = cnt[i];
        inv[i] = 1.0f / (float)(c > 1 ? c : 1);
        if (i == n - 1) rowst[n] = r + c;
    }
}

// bucket (dst>>8) pre-sort into tmpv; bucket region b = [rowp[b<<8], rowp[(b+1)<<8])
__global__ __launch_bounds__(256) void k_binscatter(const int* __restrict__ src,
                                                    const int* __restrict__ dst,
                                                    int* __restrict__ bcur,
                                                    int2* __restrict__ tmpv,
                                                    int n, int nbuck, int chunk) {
    __shared__ int lcnt[MAXBUCK];
    __shared__ int lbase[MAXBUCK];
    int t = threadIdx.x;
    for (int b = t; b < nbuck; b += 256) lcnt[b] = 0;
    __syncthreads();
    int e0 = blockIdx.x * chunk;
    int e1 = e0 + chunk; if (e1 > n) e1 = n;
    for (int e = e0 + t; e < e1; e += 256) atomicAdd(&lcnt[dst[e] >> 8], 1);
    __syncthreads();
    for (int b = t; b < nbuck; b += 256) {
        int c = lcnt[b];
        lbase[b] = c ? atomicAdd(&bcur[b], c) : 0;
        lcnt[b] = 0;  // reuse as local cursor
    }
    __syncthreads();
    for (int e = e0 + t; e < e1; e += 256) {
        int d = dst[e];
        int b = d >> 8;
        int r = atomicAdd(&lcnt[b], 1);
        tmpv[lbase[b] + r] = make_int2(src[e], d);
    }
}

// one block per bucket: all cur[]/ssrc traffic confined to this bucket's range
__global__ __launch_bounds__(256) void k_scatter2(const int2* __restrict__ tmpv,
                                                  const int* __restrict__ rowp,
                                                  int* __restrict__ cur,
                                                  int* __restrict__ ssrc,
                                                  int n, int nbuck) {
    int b = blockIdx.x;
    int s = rowp[b << 8];
    int endn = (b + 1) << 8; if (endn > n) endn = n;
    int e = rowp[endn];
    for (int i = s + threadIdx.x; i < e; i += 256) {
        int2 p = tmpv[i];
        int pos = atomicAdd(&cur[p.y], 1);
        ssrc[pos] = p.x;
    }
}

// ---------------- x (fp32) -> hi/lo planes ----------------
__global__ __launch_bounds__(256) void k_cvt(const float* __restrict__ X,
                                             unsigned short* __restrict__ Xhi,
                                             unsigned short* __restrict__ Xlo,
                                             int n) {
    int grp = threadIdx.x >> 4, l = threadIdx.x & 15;
    int i = blockIdx.x * 16 + grp;
    if (i >= n) return;
    unsigned short* ph = Xhi + (size_t)i * PST + l * 8;
    unsigned short* pl = Xlo + (size_t)i * PST + l * 8;
    if (l < 13) {
        float4 v0 = *(const float4*)(X + (size_t)i * 100 + l * 8);
        float4 v1 = (l < 12) ? *(const float4*)(X + (size_t)i * 100 + l * 8 + 4)
                             : make_float4(0.f, 0.f, 0.f, 0.f);
        float f[8] = {v0.x, v0.y, v0.z, v0.w, v1.x, v1.y, v1.z, v1.w};
        short8v hv, lv;
#pragma unroll
        for (int m = 0; m < 8; ++m) {
            unsigned short h = f2bf(f[m]);
            hv[m] = (short)h;
            lv[m] = (short)f2bf(f[m] - bf2f(h));
        }
        *(short8v*)ph = hv;
        *(short8v*)pl = lv;
    } else {
        short8v z = (short8v){0,0,0,0,0,0,0,0};
        *(short8v*)ph = z;
        *(short8v*)pl = z;
    }
}

// ---------------- mean aggregation over CSR (hi-only gather) ----------------
__global__ __launch_bounds__(256) void k_aggr(const unsigned short* __restrict__ Xhi,
                                              const int* __restrict__ ssrc,
                                              const int* __restrict__ rowst,
                                              const float* __restrict__ inv,
                                              unsigned short* __restrict__ Ahi,
                                              unsigned short* __restrict__ Alo,
                                              int n) {
    int grp = threadIdx.x >> 4;
    int l = threadIdx.x & 15;
    int node = blockIdx.x * 16 + grp;
    if (node >= n) return;
    int s = rowst[node];
    int e = rowst[node + 1];
    const bool act = l < 13;
    float a[8];
#pragma unroll
    for (int m = 0; m < 8; ++m) a[m] = 0.f;
    const size_t loff = (size_t)l * 8;

    int i = s;
    for (; i + 4 <= e; i += 4) {
        int s0 = ssrc[i], s1 = ssrc[i + 1], s2 = ssrc[i + 2], s3 = ssrc[i + 3];
        if (act) {
            short8v v0 = *(const short8v*)(Xhi + (size_t)s0 * PST + loff);
            short8v v1 = *(const short8v*)(Xhi + (size_t)s1 * PST + loff);
            short8v v2 = *(const short8v*)(Xhi + (size_t)s2 * PST + loff);
            short8v v3 = *(const short8v*)(Xhi + (size_t)s3 * PST + loff);
#pragma unroll
            for (int m = 0; m < 8; ++m)
                a[m] += bf2f((unsigned short)v0[m]) + bf2f((unsigned short)v1[m])
                      + bf2f((unsigned short)v2[m]) + bf2f((unsigned short)v3[m]);
        }
    }
    for (; i < e; ++i) {
        int s0 = ssrc[i];
        if (act) {
            short8v v0 = *(const short8v*)(Xhi + (size_t)s0 * PST + loff);
#pragma unroll
            for (int m = 0; m < 8; ++m) a[m] += bf2f((unsigned short)v0[m]);
        }
    }

    unsigned short* oh = Ahi + (size_t)node * PST + loff;
    unsigned short* ol = Alo + (size_t)node * PST + loff;
    if (act) {
        const float f = inv[node];
        short8v hv, lv;
#pragma unroll
        for (int m = 0; m < 8; ++m) {
            float v = a[m] * f;
            unsigned short h = f2bf(v);
            hv[m] = (short)h;
            lv[m] = (short)f2bf(v - bf2f(h));
        }
        *(short8v*)oh = hv;
        *(short8v*)ol = lv;
    } else {
        short8v z = (short8v){0,0,0,0,0,0,0,0};
        *(short8v*)oh = z;
        *(short8v*)ol = z;
    }
}

// ---------------- weight pack (all 3 layers in one launch) ----------------
// per layer: idx = ((part*4 + c)*7 + nt)*64 + lane; feat = c*32+(lane>>4)*8+jj;
// col = nt*16+(lane&15). part0 -> Wl, part1 -> Wr.
#define PACKN (2 * 4 * 7 * 64)
__global__ __launch_bounds__(256) void k_pack3(const float* __restrict__ W1l, const float* __restrict__ W1r,
                                               const float* __restrict__ W2l, const float* __restrict__ W2r,
                                               const float* __restrict__ W3l, const float* __restrict__ W3r,
                                               unsigned short* __restrict__ B1h, unsigned short* __restrict__ B1l,
                                               unsigned short* __restrict__ B2h, unsigned short* __restrict__ B2l,
                                               unsigned short* __restrict__ B3h, unsigned short* __restrict__ B3l) {
    int gid = blockIdx.x * 256 + threadIdx.x;
    if (gid >= 3 * PACKN) return;
    int layer = gid / PACKN;
    int idx = gid - layer * PACKN;
    const float* Wl = layer == 0 ? W1l : (layer == 1 ? W2l : W3l);
    const float* Wr = layer == 0 ? W1r : (layer == 1 ? W2r : W3r);
    unsigned short* Bh = layer == 0 ? B1h : (layer == 1 ? B2h : B3h);
    unsigned short* Bl = layer == 0 ? B1l : (layer == 1 ? B2l : B3l);
    int lane = idx & 63;
    int t = idx >> 6;
    int nt = t % 7;
    int pc = t / 7;
    int part = pc >> 2, c = pc & 3;
    int col = nt * 16 + (lane & 15);
    int fbase = c * 32 + (lane >> 4) * 8;
    const float* W = part ? Wr : Wl;
    for (int jj = 0; jj < 8; ++jj) {
        int k = fbase + jj;
        float w = (k < 100 && col < 100) ? W[k * 100 + col] : 0.f;
        unsigned short h = f2bf(w);
        Bh[(size_t)idx * 8 + jj] = h;
        Bl[(size_t)idx * 8 + jj] = f2bf(w - bf2f(h));
    }
}

// ---------------- MFMA GEMM: O = act(aggr@Wl + x@Wr + b) --------------------
// 1 wave = 16 rows (1 M-tile), N=112 (7 tiles). Per part (A,X), 4 K-chunks,
// 3-term split -> 168 MFMA/wave. 3125 waves (~3/SIMD) for latency hiding.
__global__ __launch_bounds__(256) void k_gemm(const unsigned short* __restrict__ Ahi,
                                              const unsigned short* __restrict__ Alo,
                                              const unsigned short* __restrict__ Xhi,
                                              const unsigned short* __restrict__ Xlo,
                                              const unsigned short* __restrict__ Bh,
                                              const unsigned short* __restrict__ Bl,
                                              const float* __restrict__ bias,
                                              unsigned short* __restrict__ Ohi,
                                              unsigned short* __restrict__ Olo,
                                              int relu, int n, int ntasks) {
    const int lane = threadIdx.x & 63;
    const int wv = threadIdx.x >> 6;
    const int task = blockIdx.x * 4 + wv;
    if (task >= ntasks) return;
    const int m0 = task * 16;
    const int lrow = lane & 15;
    const int lg = lane >> 4;

    f32x4 acc[7];
#pragma unroll
    for (int nt = 0; nt < 7; ++nt) acc[nt] = (f32x4){0.f, 0.f, 0.f, 0.f};

    int r0 = m0 + lrow; if (r0 >= n) r0 = n - 1;
    const size_t b0 = (size_t)r0 * PST + lg * 8;
    const unsigned short* ph[2] = {Ahi, Xhi};
    const unsigned short* pl[2] = {Alo, Xlo};

#pragma unroll
    for (int part = 0; part < 2; ++part) {
#pragma unroll
        for (int c = 0; c < 4; ++c) {
            short8v ah0 = *(const short8v*)(ph[part] + b0 + c * 32);
            short8v al0 = *(const short8v*)(pl[part] + b0 + c * 32);
            const unsigned short* bph = Bh + ((size_t)((part * 4 + c) * 7) * 64 + lane) * 8;
            const unsigned short* bpl = Bl + ((size_t)((part * 4 + c) * 7) * 64 + lane) * 8;
#pragma unroll
            for (int nt = 0; nt < 7; ++nt) {
                short8v bh = *(const short8v*)(bph + nt * 512);
                short8v bl = *(const short8v*)(bpl + nt * 512);
                acc[nt] = MF(ah0, bh, acc[nt]);
                acc[nt] = MF(ah0, bl, acc[nt]);
                acc[nt] = MF(al0, bh, acc[nt]);
            }
        }
    }

    // epilogue: C/D layout col=lane&15, row=(lane>>4)*4+reg  [HW-verified]
#pragma unroll
    for (int nt = 0; nt < 7; ++nt) {
        int col = nt * 16 + lrow;
        bool cok = col < 100;
        float bb = cok ? bias[col] : 0.f;
#pragma unroll
        for (int r = 0; r < 4; ++r) {
            int row = m0 + lg * 4 + r;
            if (cok && row < n) {
                float v = acc[nt][r] + bb;
                if (relu) v = fmaxf(v, 0.f);
                unsigned short h = f2bf(v);
                size_t o = (size_t)row * PST + col;
                Ohi[o] = h;
                Olo[o] = f2bf(v - bf2f(h));
            }
        }
    }
    // zero pad cols 100..127 (both planes); 2 lanes per row, 16 rows
    if (lane < 32) {
        int row = m0 + (lane >> 1);
        if (row < n) {
            unsigned short* op = ((lane & 1) == 0 ? Ohi : Olo) + (size_t)row * PST;
            short4 z4 = {0, 0, 0, 0};
            short8v z = (short8v){0,0,0,0,0,0,0,0};
            *(short4*)(op + 100) = z4;
            *(short8v*)(op + 104) = z;
            *(short8v*)(op + 112) = z;
            *(short8v*)(op + 120) = z;
        }
    }
}

// ---------------- pool + head: 1 block/graph ----------------
__global__ __launch_bounds__(256) void k_pool(const unsigned short* __restrict__ Hhi,
                                              const unsigned short* __restrict__ Hlo,
                                              const int* __restrict__ batch,
                                              const float* __restrict__ Wlin,
                                              const float* __restrict__ blin,
                                              float* __restrict__ out, int n) {
    int g = blockIdx.x;
    int t = threadIdx.x;
    int grp = t >> 4, l = t & 15;
    int lo = 0, hi = n;
    while (lo < hi) { int m = (lo + hi) >> 1; if (batch[m] < g) lo = m + 1; else hi = m; }
    int lo2 = lo, hi2 = n;
    while (lo2 < hi2) { int m = (lo2 + hi2) >> 1; if (batch[m] < g + 1) lo2 = m + 1; else hi2 = m; }

    const bool act = l < 13;
    float a[8];
#pragma unroll
    for (int m = 0; m < 8; ++m) a[m] = 0.f;
    const size_t loff = (size_t)l * 8;
    for (int node = lo + grp; node < lo2; node += 16) {
        if (act) {
            short8v vh = *(const short8v*)(Hhi + (size_t)node * PST + loff);
            short8v vl = *(const short8v*)(Hlo + (size_t)node * PST + loff);
#pragma unroll
            for (int m = 0; m < 8; ++m)
                a[m] += bf2f((unsigned short)vh[m]) + bf2f((unsigned short)vl[m]);
        }
    }

    __shared__ float part[16][13][8];
    if (act) {
#pragma unroll
        for (int m = 0; m < 8; ++m) part[grp][l][m] = a[m];
    }
    __syncthreads();

    __shared__ float gm[104];
    if (t < 104) {
        int fg = t >> 3, m = t & 7;
        float s = 0.f;
#pragma unroll
        for (int q = 0; q < 16; ++q) s += part[q][fg][m];
        float f = (lo2 > lo) ? 1.0f / (float)(lo2 - lo) : 0.0f;
        gm[t] = s * f;
    }
    __syncthreads();
    if (t < 2) {
        float o = blin[t];
        for (int k = 0; k < 100; ++k) o += gm[k] * Wlin[k * 2 + t];
        out[g * 2 + t] = o;
    }
}

// ---------------- launch ----------------

extern "C" void kernel_launch(void* const* d_in, const int* in_sizes, int n_in,
                              void* d_out, int out_size, void* d_ws, size_t ws_size,
                              hipStream_t stream) {
    const float* x    = (const float*)d_in[0];
    const int*   ei   = (const int*)d_in[1];
    const int*   batch= (const int*)d_in[2];
    const float* W1l  = (const float*)d_in[3];
    const float* b1   = (const float*)d_in[4];
    const float* W1r  = (const float*)d_in[5];
    const float* W2l  = (const float*)d_in[6];
    const float* b2   = (const float*)d_in[7];
    const float* W2r  = (const float*)d_in[8];
    const float* W3l  = (const float*)d_in[9];
    const float* b3   = (const float*)d_in[10];
    const float* W3r  = (const float*)d_in[11];
    const float* Wlin = (const float*)d_in[12];
    const float* blin = (const float*)d_in[13];
    float* out = (float*)d_out;

    const int n_nodes  = in_sizes[0] / 100;
    const int n_edges  = in_sizes[1] / 2;
    const int n_graphs = out_size / 2;
    const int* src = ei;
    const int* dst = ei + n_edges;

    char* ws = (char*)d_ws;
    size_t o = 0;
    auto alloc = [&](size_t bytes) { size_t r = o; o = (o + bytes + 255) & ~(size_t)255; return r; };
    int*   cnt  = (int*)(ws + alloc((size_t)n_nodes * 4));
    int*   rowp = (int*)(ws + alloc((size_t)(n_nodes + 1) * 4));
    int*   cur  = (int*)(ws + alloc((size_t)n_nodes * 4));
    int*   bsum = (int*)(ws + alloc(64 * 4));
    float* inv  = (float*)(ws + alloc((size_t)n_nodes * 4));
    int*   ssrc = (int*)(ws + alloc((size_t)n_edges * 4));
    int*   bcur = (int*)(ws + alloc(MAXBUCK * 4));
    int2*  tmpv = (int2*)(ws + alloc((size_t)n_edges * 8));
    const size_t pbytes = (size_t)n_nodes * PST * 2;  // one bf16 plane
    unsigned short* XAhi = (unsigned short*)(ws + alloc(pbytes));
    unsigned short* XAlo = (unsigned short*)(ws + alloc(pbytes));
    unsigned short* XBhi = (unsigned short*)(ws + alloc(pbytes));
    unsigned short* XBlo = (unsigned short*)(ws + alloc(pbytes));
    unsigned short* AGhi = (unsigned short*)(ws + alloc(pbytes));
    unsigned short* AGlo = (unsigned short*)(ws + alloc(pbytes));
    const size_t bfb = (size_t)PACKN * 8 * 2;
    unsigned short* B1h = (unsigned short*)(ws + alloc(bfb));
    unsigned short* B1l = (unsigned short*)(ws + alloc(bfb));
    unsigned short* B2h = (unsigned short*)(ws + alloc(bfb));
    unsigned short* B2l = (unsigned short*)(ws + alloc(bfb));
    unsigned short* B3h = (unsigned short*)(ws + alloc(bfb));
    unsigned short* B3l = (unsigned short*)(ws + alloc(bfb));

    hipMemsetAsync(cnt, 0, (size_t)n_nodes * 4, stream);

    const int eb = (n_edges + 255) / 256;
    const int sb = (n_nodes + 1023) / 1024;
    const int nb256 = (n_nodes + 255) / 256;
    const int nbuck = (n_nodes + 255) >> 8;
    const int chunk = (n_edges + 255) / 256;

    // node-level CSR offsets (bucket bases fall out of rowp since bucket=dst>>8)
    k_count<<<eb, 256, 0, stream>>>(dst, cnt, n_edges);
    k_scan1<<<sb, 1024, 0, stream>>>(cnt, rowp, bsum, n_nodes);
    k_scan3<<<nb256, 256, 0, stream>>>(cnt, rowp, bsum, cur, bcur, inv, n_nodes);
    // bucket pre-sort, then bucket-local final scatter
    k_binscatter<<<256, 256, 0, stream>>>(src, dst, bcur, tmpv, n_edges, nbuck, chunk);
    k_scatter2<<<nbuck, 256, 0, stream>>>(tmpv, rowp, cur, ssrc, n_nodes, nbuck);

    k_pack3<<<(3 * PACKN + 255) / 256, 256, 0, stream>>>(
        W1l, W1r, W2l, W2r, W3l, W3r, B1h, B1l, B2h, B2l, B3h, B3l);

    const int nb16 = (n_nodes + 15) / 16;
    const int ntasks = (n_nodes + 15) / 16;
    const int ggrid = (ntasks + 3) / 4;

    k_cvt<<<nb16, 256, 0, stream>>>(x, XAhi, XAlo, n_nodes);

    // layer 1
    k_aggr<<<nb16, 256, 0, stream>>>(XAhi, ssrc, rowp, inv, AGhi, AGlo, n_nodes);
    k_gemm<<<ggrid, 256, 0, stream>>>(AGhi, AGlo, XAhi, XAlo, B1h, B1l, b1,
                                      XBhi, XBlo, 1, n_nodes, ntasks);
    // layer 2
    k_aggr<<<nb16, 256, 0, stream>>>(XBhi, ssrc, rowp, inv, AGhi, AGlo, n_nodes);
    k_gemm<<<ggrid, 256, 0, stream>>>(AGhi, AGlo, XBhi, XBlo, B2h, B2l, b2,
                                      XAhi, XAlo, 1, n_nodes, ntasks);
    // layer 3 (no relu)
    k_aggr<<<nb16, 256, 0, stream>>>(XAhi, ssrc, rowp, inv, AGhi, AGlo, n_nodes);
    k_gemm<<<ggrid, 256, 0, stream>>>(AGhi, AGlo, XAhi, XAlo, B3h, B3l, b3,
                                      XBhi, XBlo, 0, n_nodes, ntasks);

    k_pool<<<n_graphs, 256, 0, stream>>>(XBhi, XBlo, batch, Wlin, blin, out, n_nodes);
}

// Round 10
// 243.118 us; speedup vs baseline: 2.6077x; 1.2185x over previous
//
#include <hip/hip_runtime.h>
#include <hip/hip_bf16.h>

typedef __attribute__((ext_vector_type(8))) short short8v;
typedef __attribute__((ext_vector_type(4))) float f32x4;

// Activation storage: separate hi/lo bf16 planes, stride 128 shorts (256 B).
// feats 0..99 valid, 100..127 zero pad.
#define PST 128
#define PSTL 136   // LDS row stride (shorts): 272B = 16B-aligned, 4-bank row skew
#define MAXBUCK 1024

static __device__ inline unsigned short f2bf(float x) {
    union { float f; unsigned int u; } c; c.f = x;
    unsigned int r = (c.u + 0x7FFFu + ((c.u >> 16) & 1u)) >> 16;
    return (unsigned short)r;
}
static __device__ inline float bf2f(unsigned short h) {
    union { float f; unsigned int u; } c; c.u = ((unsigned int)h) << 16;
    return c.f;
}
static __device__ inline f32x4 MF(short8v a, short8v b, f32x4 c) {
    return __builtin_amdgcn_mfma_f32_16x16x32_bf16(a, b, c, 0, 0, 0);
}

// ---------------- bucket CSR build (bucket = dst>>8, 256 nodes) -------------

__global__ __launch_bounds__(256) void k_bincount(const int* __restrict__ dst,
                                                  int* __restrict__ bcnt,
                                                  int n, int nbuck, int chunk) {
    __shared__ int lcnt[MAXBUCK];
    int t = threadIdx.x;
    for (int b = t; b < nbuck; b += 256) lcnt[b] = 0;
    __syncthreads();
    int e0 = blockIdx.x * chunk;
    int e1 = e0 + chunk; if (e1 > n) e1 = n;
    for (int e = e0 + t; e < e1; e += 256) atomicAdd(&lcnt[dst[e] >> 8], 1);
    __syncthreads();
    for (int b = t; b < nbuck; b += 256)
        if (lcnt[b]) atomicAdd(&bcnt[b], lcnt[b]);
}

__global__ __launch_bounds__(1024) void k_binscan(const int* __restrict__ bcnt,
                                                  int* __restrict__ bbase,
                                                  int* __restrict__ bcur,
                                                  int* __restrict__ rowp,
                                                  int nbuck, int n_nodes, int n_edges) {
    __shared__ int tmp[1024];
    int t = threadIdx.x;
    int v = (t < nbuck) ? bcnt[t] : 0;
    tmp[t] = v;
    __syncthreads();
    for (int off = 1; off < 1024; off <<= 1) {
        int u = 0;
        if (t >= off) u = tmp[t - off];
        __syncthreads();
        if (t >= off) tmp[t] += u;
        __syncthreads();
    }
    if (t < nbuck) { int b = tmp[t] - v; bbase[t] = b; bcur[t] = b; }
    if (t == 0) rowp[n_nodes] = n_edges;
}

// bucket pre-sort of (src,dst) pairs into tmpv
__global__ __launch_bounds__(256) void k_binscatter(const int* __restrict__ src,
                                                    const int* __restrict__ dst,
                                                    int* __restrict__ bcur,
                                                    int2* __restrict__ tmpv,
                                                    int n, int nbuck, int chunk) {
    __shared__ int lcnt[MAXBUCK];
    __shared__ int lbase[MAXBUCK];
    int t = threadIdx.x;
    for (int b = t; b < nbuck; b += 256) lcnt[b] = 0;
    __syncthreads();
    int e0 = blockIdx.x * chunk;
    int e1 = e0 + chunk; if (e1 > n) e1 = n;
    for (int e = e0 + t; e < e1; e += 256) atomicAdd(&lcnt[dst[e] >> 8], 1);
    __syncthreads();
    for (int b = t; b < nbuck; b += 256) {
        int c = lcnt[b];
        lbase[b] = c ? atomicAdd(&bcur[b], c) : 0;
        lcnt[b] = 0;  // reuse as local cursor
    }
    __syncthreads();
    for (int e = e0 + t; e < e1; e += 256) {
        int d = dst[e];
        int b = d >> 8;
        int r = atomicAdd(&lcnt[b], 1);
        tmpv[lbase[b] + r] = make_int2(src[e], d);
    }
}

// one block per bucket: LDS histogram+scan -> rowp/inv slice + ssrc scatter
__global__ __launch_bounds__(256) void k_build(const int2* __restrict__ tmpv,
                                               const int* __restrict__ bbase,
                                               int* __restrict__ rowp,
                                               float* __restrict__ inv,
                                               int* __restrict__ ssrc,
                                               int n_nodes, int n_edges, int nbuck) {
    __shared__ int hist[256];
    __shared__ int scan[256];
    __shared__ int curs[256];
    int b = blockIdx.x;
    int t = threadIdx.x;
    int s = bbase[b];
    int e = (b + 1 < nbuck) ? bbase[b + 1] : n_edges;
    hist[t] = 0;
    __syncthreads();
    for (int i = s + t; i < e; i += 256) atomicAdd(&hist[tmpv[i].y & 255], 1);
    __syncthreads();
    int v = hist[t];
    scan[t] = v;
    __syncthreads();
    for (int off = 1; off < 256; off <<= 1) {
        int u = 0;
        if (t >= off) u = scan[t - off];
        __syncthreads();
        if (t >= off) scan[t] += u;
        __syncthreads();
    }
    int excl = scan[t] - v;
    curs[t] = excl;
    int node = (b << 8) + t;
    if (node < n_nodes) {
        rowp[node] = s + excl;
        inv[node] = 1.0f / (float)(v > 1 ? v : 1);
    }
    __syncthreads();
    for (int i = s + t; i < e; i += 256) {
        int2 p = tmpv[i];
        int r = atomicAdd(&curs[p.y & 255], 1);
        ssrc[s + r] = p.x;
    }
}

// ---------------- x (fp32) -> hi/lo planes ----------------
__global__ __launch_bounds__(256) void k_cvt(const float* __restrict__ X,
                                             unsigned short* __restrict__ Xhi,
                                             unsigned short* __restrict__ Xlo,
                                             int n) {
    int grp = threadIdx.x >> 4, l = threadIdx.x & 15;
    int i = blockIdx.x * 16 + grp;
    if (i >= n) return;
    unsigned short* ph = Xhi + (size_t)i * PST + l * 8;
    unsigned short* pl = Xlo + (size_t)i * PST + l * 8;
    if (l < 13) {
        float4 v0 = *(const float4*)(X + (size_t)i * 100 + l * 8);
        float4 v1 = (l < 12) ? *(const float4*)(X + (size_t)i * 100 + l * 8 + 4)
                             : make_float4(0.f, 0.f, 0.f, 0.f);
        float f[8] = {v0.x, v0.y, v0.z, v0.w, v1.x, v1.y, v1.z, v1.w};
        short8v hv, lv;
#pragma unroll
        for (int m = 0; m < 8; ++m) {
            unsigned short h = f2bf(f[m]);
            hv[m] = (short)h;
            lv[m] = (short)f2bf(f[m] - bf2f(h));
        }
        *(short8v*)ph = hv;
        *(short8v*)pl = lv;
    } else {
        short8v z = (short8v){0,0,0,0,0,0,0,0};
        *(short8v*)ph = z;
        *(short8v*)pl = z;
    }
}

// ---------------- weight pack (all 3 layers in one launch) ----------------
#define PACKN (2 * 4 * 7 * 64)
__global__ __launch_bounds__(256) void k_pack3(const float* __restrict__ W1l, const float* __restrict__ W1r,
                                               const float* __restrict__ W2l, const float* __restrict__ W2r,
                                               const float* __restrict__ W3l, const float* __restrict__ W3r,
                                               unsigned short* __restrict__ B1h, unsigned short* __restrict__ B1l,
                                               unsigned short* __restrict__ B2h, unsigned short* __restrict__ B2l,
                                               unsigned short* __restrict__ B3h, unsigned short* __restrict__ B3l) {
    int gid = blockIdx.x * 256 + threadIdx.x;
    if (gid >= 3 * PACKN) return;
    int layer = gid / PACKN;
    int idx = gid - layer * PACKN;
    const float* Wl = layer == 0 ? W1l : (layer == 1 ? W2l : W3l);
    const float* Wr = layer == 0 ? W1r : (layer == 1 ? W2r : W3r);
    unsigned short* Bh = layer == 0 ? B1h : (layer == 1 ? B2h : B3h);
    unsigned short* Bl = layer == 0 ? B1l : (layer == 1 ? B2l : B3l);
    int lane = idx & 63;
    int t = idx >> 6;
    int nt = t % 7;
    int pc = t / 7;
    int part = pc >> 2, c = pc & 3;
    int col = nt * 16 + (lane & 15);
    int fbase = c * 32 + (lane >> 4) * 8;
    const float* W = part ? Wr : Wl;
    for (int jj = 0; jj < 8; ++jj) {
        int k = fbase + jj;
        float w = (k < 100 && col < 100) ? W[k * 100 + col] : 0.f;
        unsigned short h = f2bf(w);
        Bh[(size_t)idx * 8 + jj] = h;
        Bl[(size_t)idx * 8 + jj] = f2bf(w - bf2f(h));
    }
}

// ---------------- fused layer: aggr (LDS relay) + MFMA GEMM -----------------
// 64 nodes/block. Phase 1: 16 lanes/node gather-mean (hi-only), deposit hi/lo
// bf16 into LDS. Phase 2: wave w MFMAs rows [base+16w, base+16w+16):
// O = act(aggr@Wl + x@Wr + b), A-frags from LDS, x/B-frags from global.
__global__ __launch_bounds__(256) void k_layer(const unsigned short* __restrict__ Xhi,
                                               const unsigned short* __restrict__ Xlo,
                                               const int* __restrict__ ssrc,
                                               const int* __restrict__ rowp,
                                               const float* __restrict__ inv,
                                               const unsigned short* __restrict__ Bh,
                                               const unsigned short* __restrict__ Bl,
                                               const float* __restrict__ bias,
                                               unsigned short* __restrict__ Ohi,
                                               unsigned short* __restrict__ Olo,
                                               int relu, int n) {
    __shared__ unsigned short lds_h[64][PSTL];
    __shared__ unsigned short lds_l[64][PSTL];
    const int t = threadIdx.x;
    const int base = blockIdx.x * 64;

    // ---- phase 1: gather-mean for 64 nodes ----
    {
        const int grp = t >> 4, l = t & 15;
        const bool act = l < 13;
        const size_t loff = (size_t)l * 8;
        const short8v z = (short8v){0,0,0,0,0,0,0,0};
#pragma unroll
        for (int it = 0; it < 4; ++it) {
            const int lr = it * 16 + grp;       // LDS row
            const int node = base + lr;
            if (node < n) {
                int s = rowp[node];
                int e = rowp[node + 1];
                float a[8];
#pragma unroll
                for (int m = 0; m < 8; ++m) a[m] = 0.f;
                int i = s;
                for (; i + 4 <= e; i += 4) {
                    int s0 = ssrc[i], s1 = ssrc[i + 1], s2 = ssrc[i + 2], s3 = ssrc[i + 3];
                    if (act) {
                        short8v v0 = *(const short8v*)(Xhi + (size_t)s0 * PST + loff);
                        short8v v1 = *(const short8v*)(Xhi + (size_t)s1 * PST + loff);
                        short8v v2 = *(const short8v*)(Xhi + (size_t)s2 * PST + loff);
                        short8v v3 = *(const short8v*)(Xhi + (size_t)s3 * PST + loff);
#pragma unroll
                        for (int m = 0; m < 8; ++m)
                            a[m] += bf2f((unsigned short)v0[m]) + bf2f((unsigned short)v1[m])
                                  + bf2f((unsigned short)v2[m]) + bf2f((unsigned short)v3[m]);
                    }
                }
                for (; i < e; ++i) {
                    int s0 = ssrc[i];
                    if (act) {
                        short8v v0 = *(const short8v*)(Xhi + (size_t)s0 * PST + loff);
#pragma unroll
                        for (int m = 0; m < 8; ++m) a[m] += bf2f((unsigned short)v0[m]);
                    }
                }
                if (act) {
                    const float f = inv[node];
                    short8v hv, lv;
#pragma unroll
                    for (int m = 0; m < 8; ++m) {
                        float v = a[m] * f;
                        unsigned short h = f2bf(v);
                        hv[m] = (short)h;
                        lv[m] = (short)f2bf(v - bf2f(h));
                    }
                    *(short8v*)&lds_h[lr][l * 8] = hv;
                    *(short8v*)&lds_l[lr][l * 8] = lv;
                } else {  // lanes 13..15 zero pad cols 104..127
                    *(short8v*)&lds_h[lr][l * 8] = z;
                    *(short8v*)&lds_l[lr][l * 8] = z;
                }
            } else {  // zero whole LDS row (cols 0..127)
                *(short8v*)&lds_h[lr][l * 8] = z;
                *(short8v*)&lds_l[lr][l * 8] = z;
            }
        }
    }
    __syncthreads();

    // ---- phase 2: MFMA GEMM, 1 wave = 16 rows ----
    const int lane = t & 63;
    const int wv = t >> 6;
    const int m0 = base + wv * 16;
    const int lrow = lane & 15;
    const int lg = lane >> 4;
    const int ldr = wv * 16 + lrow;

    f32x4 acc[7];
#pragma unroll
    for (int nt = 0; nt < 7; ++nt) acc[nt] = (f32x4){0.f, 0.f, 0.f, 0.f};

    int r0 = m0 + lrow; if (r0 >= n) r0 = n - 1;
    const size_t b0 = (size_t)r0 * PST + lg * 8;

    // part 0: aggr @ Wl (A-frags from LDS)
#pragma unroll
    for (int c = 0; c < 4; ++c) {
        short8v ah0 = *(const short8v*)&lds_h[ldr][c * 32 + lg * 8];
        short8v al0 = *(const short8v*)&lds_l[ldr][c * 32 + lg * 8];
        const unsigned short* bph = Bh + ((size_t)(c * 7) * 64 + lane) * 8;
        const unsigned short* bpl = Bl + ((size_t)(c * 7) * 64 + lane) * 8;
#pragma unroll
        for (int nt = 0; nt < 7; ++nt) {
            short8v bh = *(const short8v*)(bph + nt * 512);
            short8v bl = *(const short8v*)(bpl + nt * 512);
            acc[nt] = MF(ah0, bh, acc[nt]);
            acc[nt] = MF(ah0, bl, acc[nt]);
            acc[nt] = MF(al0, bh, acc[nt]);
        }
    }
    // part 1: x @ Wr (A-frags from global planes)
#pragma unroll
    for (int c = 0; c < 4; ++c) {
        short8v ah0 = *(const short8v*)(Xhi + b0 + c * 32);
        short8v al0 = *(const short8v*)(Xlo + b0 + c * 32);
        const unsigned short* bph = Bh + ((size_t)((4 + c) * 7) * 64 + lane) * 8;
        const unsigned short* bpl = Bl + ((size_t)((4 + c) * 7) * 64 + lane) * 8;
#pragma unroll
        for (int nt = 0; nt < 7; ++nt) {
            short8v bh = *(const short8v*)(bph + nt * 512);
            short8v bl = *(const short8v*)(bpl + nt * 512);
            acc[nt] = MF(ah0, bh, acc[nt]);
            acc[nt] = MF(ah0, bl, acc[nt]);
            acc[nt] = MF(al0, bh, acc[nt]);
        }
    }

    // epilogue: C/D layout col=lane&15, row=(lane>>4)*4+reg  [HW-verified]
#pragma unroll
    for (int nt = 0; nt < 7; ++nt) {
        int col = nt * 16 + lrow;
        bool cok = col < 100;
        float bb = cok ? bias[col] : 0.f;
#pragma unroll
        for (int r = 0; r < 4; ++r) {
            int row = m0 + lg * 4 + r;
            if (cok && row < n) {
                float v = acc[nt][r] + bb;
                if (relu) v = fmaxf(v, 0.f);
                unsigned short h = f2bf(v);
                size_t o = (size_t)row * PST + col;
                Ohi[o] = h;
                Olo[o] = f2bf(v - bf2f(h));
            }
        }
    }
    // zero pad cols 100..127 (both planes); 2 lanes per row, 16 rows
    if (lane < 32) {
        int row = m0 + (lane >> 1);
        if (row < n) {
            unsigned short* op = ((lane & 1) == 0 ? Ohi : Olo) + (size_t)row * PST;
            short4 z4 = {0, 0, 0, 0};
            short8v z = (short8v){0,0,0,0,0,0,0,0};
            *(short4*)(op + 100) = z4;
            *(short8v*)(op + 104) = z;
            *(short8v*)(op + 112) = z;
            *(short8v*)(op + 120) = z;
        }
    }
}

// ---------------- pool + head: 1 block/graph ----------------
__global__ __launch_bounds__(256) void k_pool(const unsigned short* __restrict__ Hhi,
                                              const unsigned short* __restrict__ Hlo,
                                              const int* __restrict__ batch,
                                              const float* __restrict__ Wlin,
                                              const float* __restrict__ blin,
                                              float* __restrict__ out, int n) {
    int g = blockIdx.x;
    int t = threadIdx.x;
    int grp = t >> 4, l = t & 15;
    int lo = 0, hi = n;
    while (lo < hi) { int m = (lo + hi) >> 1; if (batch[m] < g) lo = m + 1; else hi = m; }
    int lo2 = lo, hi2 = n;
    while (lo2 < hi2) { int m = (lo2 + hi2) >> 1; if (batch[m] < g + 1) lo2 = m + 1; else hi2 = m; }

    const bool act = l < 13;
    float a[8];
#pragma unroll
    for (int m = 0; m < 8; ++m) a[m] = 0.f;
    const size_t loff = (size_t)l * 8;
    for (int node = lo + grp; node < lo2; node += 16) {
        if (act) {
            short8v vh = *(const short8v*)(Hhi + (size_t)node * PST + loff);
            short8v vl = *(const short8v*)(Hlo + (size_t)node * PST + loff);
#pragma unroll
            for (int m = 0; m < 8; ++m)
                a[m] += bf2f((unsigned short)vh[m]) + bf2f((unsigned short)vl[m]);
        }
    }

    __shared__ float part[16][13][8];
    if (act) {
#pragma unroll
        for (int m = 0; m < 8; ++m) part[grp][l][m] = a[m];
    }
    __syncthreads();

    __shared__ float gm[104];
    if (t < 104) {
        int fg = t >> 3, m = t & 7;
        float s = 0.f;
#pragma unroll
        for (int q = 0; q < 16; ++q) s += part[q][fg][m];
        float f = (lo2 > lo) ? 1.0f / (float)(lo2 - lo) : 0.0f;
        gm[t] = s * f;
    }
    __syncthreads();
    if (t < 2) {
        float o = blin[t];
        for (int k = 0; k < 100; ++k) o += gm[k] * Wlin[k * 2 + t];
        out[g * 2 + t] = o;
    }
}

// ---------------- launch ----------------

extern "C" void kernel_launch(void* const* d_in, const int* in_sizes, int n_in,
                              void* d_out, int out_size, void* d_ws, size_t ws_size,
                              hipStream_t stream) {
    const float* x    = (const float*)d_in[0];
    const int*   ei   = (const int*)d_in[1];
    const int*   batch= (const int*)d_in[2];
    const float* W1l  = (const float*)d_in[3];
    const float* b1   = (const float*)d_in[4];
    const float* W1r  = (const float*)d_in[5];
    const float* W2l  = (const float*)d_in[6];
    const float* b2   = (const float*)d_in[7];
    const float* W2r  = (const float*)d_in[8];
    const float* W3l  = (const float*)d_in[9];
    const float* b3   = (const float*)d_in[10];
    const float* W3r  = (const float*)d_in[11];
    const float* Wlin = (const float*)d_in[12];
    const float* blin = (const float*)d_in[13];
    float* out = (float*)d_out;

    const int n_nodes  = in_sizes[0] / 100;
    const int n_edges  = in_sizes[1] / 2;
    const int n_graphs = out_size / 2;
    const int* src = ei;
    const int* dst = ei + n_edges;

    char* ws = (char*)d_ws;
    size_t o = 0;
    auto alloc = [&](size_t bytes) { size_t r = o; o = (o + bytes + 255) & ~(size_t)255; return r; };
    int*   rowp = (int*)(ws + alloc((size_t)(n_nodes + 1) * 4));
    float* inv  = (float*)(ws + alloc((size_t)n_nodes * 4));
    int*   ssrc = (int*)(ws + alloc((size_t)n_edges * 4));
    int*   bcnt = (int*)(ws + alloc(MAXBUCK * 4));
    int*   bbase= (int*)(ws + alloc(MAXBUCK * 4));
    int*   bcur = (int*)(ws + alloc(MAXBUCK * 4));
    int2*  tmpv = (int2*)(ws + alloc((size_t)n_edges * 8));
    const size_t pbytes = (size_t)n_nodes * PST * 2;  // one bf16 plane
    unsigned short* XAhi = (unsigned short*)(ws + alloc(pbytes));
    unsigned short* XAlo = (unsigned short*)(ws + alloc(pbytes));
    unsigned short* XBhi = (unsigned short*)(ws + alloc(pbytes));
    unsigned short* XBlo = (unsigned short*)(ws + alloc(pbytes));
    const size_t bfb = (size_t)PACKN * 8 * 2;
    unsigned short* B1h = (unsigned short*)(ws + alloc(bfb));
    unsigned short* B1l = (unsigned short*)(ws + alloc(bfb));
    unsigned short* B2h = (unsigned short*)(ws + alloc(bfb));
    unsigned short* B2l = (unsigned short*)(ws + alloc(bfb));
    unsigned short* B3h = (unsigned short*)(ws + alloc(bfb));
    unsigned short* B3l = (unsigned short*)(ws + alloc(bfb));

    hipMemsetAsync(bcnt, 0, MAXBUCK * 4, stream);

    const int nbuck = (n_nodes + 255) >> 8;
    const int chunk = (n_edges + 255) / 256;

    // bucket CSR build (no node-level global pass)
    k_bincount<<<256, 256, 0, stream>>>(dst, bcnt, n_edges, nbuck, chunk);
    k_binscan<<<1, 1024, 0, stream>>>(bcnt, bbase, bcur, rowp, nbuck, n_nodes, n_edges);
    k_binscatter<<<256, 256, 0, stream>>>(src, dst, bcur, tmpv, n_edges, nbuck, chunk);
    k_build<<<nbuck, 256, 0, stream>>>(tmpv, bbase, rowp, inv, ssrc,
                                       n_nodes, n_edges, nbuck);

    k_pack3<<<(3 * PACKN + 255) / 256, 256, 0, stream>>>(
        W1l, W1r, W2l, W2r, W3l, W3r, B1h, B1l, B2h, B2l, B3h, B3l);

    const int nb16 = (n_nodes + 15) / 16;
    const int lgrid = (n_nodes + 63) / 64;

    k_cvt<<<nb16, 256, 0, stream>>>(x, XAhi, XAlo, n_nodes);

    // fused layers: aggr(LDS) + gemm
    k_layer<<<lgrid, 256, 0, stream>>>(XAhi, XAlo, ssrc, rowp, inv, B1h, B1l, b1,
                                       XBhi, XBlo, 1, n_nodes);
    k_layer<<<lgrid, 256, 0, stream>>>(XBhi, XBlo, ssrc, rowp, inv, B2h, B2l, b2,
                                       XAhi, XAlo, 1, n_nodes);
    k_layer<<<lgrid, 256, 0, stream>>>(XAhi, XAlo, ssrc, rowp, inv, B3h, B3l, b3,
                                       XBhi, XBlo, 0, n_nodes);

    k_pool<<<n_graphs, 256, 0, stream>>>(XBhi, XBlo, batch, Wlin, blin, out, n_nodes);
}

// Round 11
// 235.313 us; speedup vs baseline: 2.6942x; 1.0332x over previous
//
#include <hip/hip_runtime.h>
#include <hip/hip_bf16.h>

typedef __attribute__((ext_vector_type(8))) short short8v;
typedef __attribute__((ext_vector_type(4))) float f32x4;

// Activation storage: separate hi/lo bf16 planes, stride 128 shorts (256 B).
// feats 0..99 valid, 100..127 zero pad.
#define PST 128
#define PSTL 136   // LDS row stride (shorts): 272B = 16B-aligned, 4-bank row skew
#define MAXBUCK 1024

static __device__ inline unsigned short f2bf(float x) {
    union { float f; unsigned int u; } c; c.f = x;
    unsigned int r = (c.u + 0x7FFFu + ((c.u >> 16) & 1u)) >> 16;
    return (unsigned short)r;
}
static __device__ inline float bf2f(unsigned short h) {
    union { float f; unsigned int u; } c; c.u = ((unsigned int)h) << 16;
    return c.f;
}
static __device__ inline f32x4 MF(short8v a, short8v b, f32x4 c) {
    return __builtin_amdgcn_mfma_f32_16x16x32_bf16(a, b, c, 0, 0, 0);
}

// ---------------- bucket CSR build (bucket = dst>>8, 256 nodes) -------------

__global__ __launch_bounds__(256) void k_bincount(const int* __restrict__ dst,
                                                  int* __restrict__ bcnt,
                                                  int n, int nbuck, int chunk) {
    __shared__ int lcnt[MAXBUCK];
    int t = threadIdx.x;
    for (int b = t; b < nbuck; b += 256) lcnt[b] = 0;
    __syncthreads();
    int e0 = blockIdx.x * chunk;
    int e1 = e0 + chunk; if (e1 > n) e1 = n;
    for (int e = e0 + t; e < e1; e += 256) atomicAdd(&lcnt[dst[e] >> 8], 1);
    __syncthreads();
    for (int b = t; b < nbuck; b += 256)
        if (lcnt[b]) atomicAdd(&bcnt[b], lcnt[b]);
}

__global__ __launch_bounds__(1024) void k_binscan(const int* __restrict__ bcnt,
                                                  int* __restrict__ bbase,
                                                  int* __restrict__ bcur,
                                                  int* __restrict__ rowp,
                                                  int nbuck, int n_nodes, int n_edges) {
    __shared__ int tmp[1024];
    int t = threadIdx.x;
    int v = (t < nbuck) ? bcnt[t] : 0;
    tmp[t] = v;
    __syncthreads();
    for (int off = 1; off < 1024; off <<= 1) {
        int u = 0;
        if (t >= off) u = tmp[t - off];
        __syncthreads();
        if (t >= off) tmp[t] += u;
        __syncthreads();
    }
    if (t < nbuck) { int b = tmp[t] - v; bbase[t] = b; bcur[t] = b; }
    if (t == 0) rowp[n_nodes] = n_edges;
}

// bucket pre-sort of (src,dst) pairs into tmpv
__global__ __launch_bounds__(256) void k_binscatter(const int* __restrict__ src,
                                                    const int* __restrict__ dst,
                                                    int* __restrict__ bcur,
                                                    int2* __restrict__ tmpv,
                                                    int n, int nbuck, int chunk) {
    __shared__ int lcnt[MAXBUCK];
    __shared__ int lbase[MAXBUCK];
    int t = threadIdx.x;
    for (int b = t; b < nbuck; b += 256) lcnt[b] = 0;
    __syncthreads();
    int e0 = blockIdx.x * chunk;
    int e1 = e0 + chunk; if (e1 > n) e1 = n;
    for (int e = e0 + t; e < e1; e += 256) atomicAdd(&lcnt[dst[e] >> 8], 1);
    __syncthreads();
    for (int b = t; b < nbuck; b += 256) {
        int c = lcnt[b];
        lbase[b] = c ? atomicAdd(&bcur[b], c) : 0;
        lcnt[b] = 0;  // reuse as local cursor
    }
    __syncthreads();
    for (int e = e0 + t; e < e1; e += 256) {
        int d = dst[e];
        int b = d >> 8;
        int r = atomicAdd(&lcnt[b], 1);
        tmpv[lbase[b] + r] = make_int2(src[e], d);
    }
}

// one block per bucket: LDS histogram+scan -> rowp/inv slice + ssrc scatter
__global__ __launch_bounds__(256) void k_build(const int2* __restrict__ tmpv,
                                               const int* __restrict__ bbase,
                                               int* __restrict__ rowp,
                                               float* __restrict__ inv,
                                               int* __restrict__ ssrc,
                                               int n_nodes, int n_edges, int nbuck) {
    __shared__ int hist[256];
    __shared__ int scan[256];
    __shared__ int curs[256];
    int b = blockIdx.x;
    int t = threadIdx.x;
    int s = bbase[b];
    int e = (b + 1 < nbuck) ? bbase[b + 1] : n_edges;
    hist[t] = 0;
    __syncthreads();
    for (int i = s + t; i < e; i += 256) atomicAdd(&hist[tmpv[i].y & 255], 1);
    __syncthreads();
    int v = hist[t];
    scan[t] = v;
    __syncthreads();
    for (int off = 1; off < 256; off <<= 1) {
        int u = 0;
        if (t >= off) u = scan[t - off];
        __syncthreads();
        if (t >= off) scan[t] += u;
        __syncthreads();
    }
    int excl = scan[t] - v;
    curs[t] = excl;
    int node = (b << 8) + t;
    if (node < n_nodes) {
        rowp[node] = s + excl;
        inv[node] = 1.0f / (float)(v > 1 ? v : 1);
    }
    __syncthreads();
    for (int i = s + t; i < e; i += 256) {
        int2 p = tmpv[i];
        int r = atomicAdd(&curs[p.y & 255], 1);
        ssrc[s + r] = p.x;
    }
}

// ---------------- x (fp32) -> hi/lo planes ----------------
__global__ __launch_bounds__(256) void k_cvt(const float* __restrict__ X,
                                             unsigned short* __restrict__ Xhi,
                                             unsigned short* __restrict__ Xlo,
                                             int n) {
    int grp = threadIdx.x >> 4, l = threadIdx.x & 15;
    int i = blockIdx.x * 16 + grp;
    if (i >= n) return;
    unsigned short* ph = Xhi + (size_t)i * PST + l * 8;
    unsigned short* pl = Xlo + (size_t)i * PST + l * 8;
    if (l < 13) {
        float4 v0 = *(const float4*)(X + (size_t)i * 100 + l * 8);
        float4 v1 = (l < 12) ? *(const float4*)(X + (size_t)i * 100 + l * 8 + 4)
                             : make_float4(0.f, 0.f, 0.f, 0.f);
        float f[8] = {v0.x, v0.y, v0.z, v0.w, v1.x, v1.y, v1.z, v1.w};
        short8v hv, lv;
#pragma unroll
        for (int m = 0; m < 8; ++m) {
            unsigned short h = f2bf(f[m]);
            hv[m] = (short)h;
            lv[m] = (short)f2bf(f[m] - bf2f(h));
        }
        *(short8v*)ph = hv;
        *(short8v*)pl = lv;
    } else {
        short8v z = (short8v){0,0,0,0,0,0,0,0};
        *(short8v*)ph = z;
        *(short8v*)pl = z;
    }
}

// ---------------- weight pack (all 3 layers in one launch) ----------------
#define PACKN (2 * 4 * 7 * 64)
__global__ __launch_bounds__(256) void k_pack3(const float* __restrict__ W1l, const float* __restrict__ W1r,
                                               const float* __restrict__ W2l, const float* __restrict__ W2r,
                                               const float* __restrict__ W3l, const float* __restrict__ W3r,
                                               unsigned short* __restrict__ B1h, unsigned short* __restrict__ B1l,
                                               unsigned short* __restrict__ B2h, unsigned short* __restrict__ B2l,
                                               unsigned short* __restrict__ B3h, unsigned short* __restrict__ B3l) {
    int gid = blockIdx.x * 256 + threadIdx.x;
    if (gid >= 3 * PACKN) return;
    int layer = gid / PACKN;
    int idx = gid - layer * PACKN;
    const float* Wl = layer == 0 ? W1l : (layer == 1 ? W2l : W3l);
    const float* Wr = layer == 0 ? W1r : (layer == 1 ? W2r : W3r);
    unsigned short* Bh = layer == 0 ? B1h : (layer == 1 ? B2h : B3h);
    unsigned short* Bl = layer == 0 ? B1l : (layer == 1 ? B2l : B3l);
    int lane = idx & 63;
    int t = idx >> 6;
    int nt = t % 7;
    int pc = t / 7;
    int part = pc >> 2, c = pc & 3;
    int col = nt * 16 + (lane & 15);
    int fbase = c * 32 + (lane >> 4) * 8;
    const float* W = part ? Wr : Wl;
    for (int jj = 0; jj < 8; ++jj) {
        int k = fbase + jj;
        float w = (k < 100 && col < 100) ? W[k * 100 + col] : 0.f;
        unsigned short h = f2bf(w);
        Bh[(size_t)idx * 8 + jj] = h;
        Bl[(size_t)idx * 8 + jj] = f2bf(w - bf2f(h));
    }
}

// ---------------- fused layer: aggr (LDS relay) + MFMA GEMM -----------------
// 32 nodes / 128 threads / 2 waves per block (fine granularity: ~6 blocks/CU
// resident -> gather-phase blocks overlap MFMA-phase blocks on the CU).
// Phase 1: 16 lanes/node gather-mean (hi-only), hi/lo bf16 into LDS.
// Phase 2: wave w MFMAs rows [base+16w, base+16w+16).
__global__ __launch_bounds__(128) void k_layer(const unsigned short* __restrict__ Xhi,
                                               const unsigned short* __restrict__ Xlo,
                                               const int* __restrict__ ssrc,
                                               const int* __restrict__ rowp,
                                               const float* __restrict__ inv,
                                               const unsigned short* __restrict__ Bh,
                                               const unsigned short* __restrict__ Bl,
                                               const float* __restrict__ bias,
                                               unsigned short* __restrict__ Ohi,
                                               unsigned short* __restrict__ Olo,
                                               int relu, int n) {
    __shared__ unsigned short lds_h[32][PSTL];
    __shared__ unsigned short lds_l[32][PSTL];
    const int t = threadIdx.x;
    const int base = blockIdx.x * 32;

    // ---- phase 1: gather-mean for 32 nodes (8 groups x 4 iters) ----
    {
        const int grp = t >> 4, l = t & 15;
        const bool act = l < 13;
        const size_t loff = (size_t)l * 8;
        const short8v z = (short8v){0,0,0,0,0,0,0,0};
#pragma unroll
        for (int it = 0; it < 4; ++it) {
            const int lr = it * 8 + grp;        // LDS row
            const int node = base + lr;
            if (node < n) {
                int s = rowp[node];
                int e = rowp[node + 1];
                float a[8];
#pragma unroll
                for (int m = 0; m < 8; ++m) a[m] = 0.f;
                int i = s;
                for (; i + 4 <= e; i += 4) {
                    int s0 = ssrc[i], s1 = ssrc[i + 1], s2 = ssrc[i + 2], s3 = ssrc[i + 3];
                    if (act) {
                        short8v v0 = *(const short8v*)(Xhi + (size_t)s0 * PST + loff);
                        short8v v1 = *(const short8v*)(Xhi + (size_t)s1 * PST + loff);
                        short8v v2 = *(const short8v*)(Xhi + (size_t)s2 * PST + loff);
                        short8v v3 = *(const short8v*)(Xhi + (size_t)s3 * PST + loff);
#pragma unroll
                        for (int m = 0; m < 8; ++m)
                            a[m] += bf2f((unsigned short)v0[m]) + bf2f((unsigned short)v1[m])
                                  + bf2f((unsigned short)v2[m]) + bf2f((unsigned short)v3[m]);
                    }
                }
                for (; i < e; ++i) {
                    int s0 = ssrc[i];
                    if (act) {
                        short8v v0 = *(const short8v*)(Xhi + (size_t)s0 * PST + loff);
#pragma unroll
                        for (int m = 0; m < 8; ++m) a[m] += bf2f((unsigned short)v0[m]);
                    }
                }
                if (act) {
                    const float f = inv[node];
                    short8v hv, lv;
#pragma unroll
                    for (int m = 0; m < 8; ++m) {
                        float v = a[m] * f;
                        unsigned short h = f2bf(v);
                        hv[m] = (short)h;
                        lv[m] = (short)f2bf(v - bf2f(h));
                    }
                    *(short8v*)&lds_h[lr][l * 8] = hv;
                    *(short8v*)&lds_l[lr][l * 8] = lv;
                } else {  // lanes 13..15 zero pad cols 104..127
                    *(short8v*)&lds_h[lr][l * 8] = z;
                    *(short8v*)&lds_l[lr][l * 8] = z;
                }
            } else {  // zero whole LDS row (cols 0..127)
                *(short8v*)&lds_h[lr][l * 8] = z;
                *(short8v*)&lds_l[lr][l * 8] = z;
            }
        }
    }
    __syncthreads();

    // ---- phase 2: MFMA GEMM, 1 wave = 16 rows ----
    const int lane = t & 63;
    const int wv = t >> 6;
    const int m0 = base + wv * 16;
    const int lrow = lane & 15;
    const int lg = lane >> 4;
    const int ldr = wv * 16 + lrow;

    f32x4 acc[7];
#pragma unroll
    for (int nt = 0; nt < 7; ++nt) acc[nt] = (f32x4){0.f, 0.f, 0.f, 0.f};

    int r0 = m0 + lrow; if (r0 >= n) r0 = n - 1;
    const size_t b0 = (size_t)r0 * PST + lg * 8;

    // part 0: aggr @ Wl (A-frags from LDS)
#pragma unroll
    for (int c = 0; c < 4; ++c) {
        short8v ah0 = *(const short8v*)&lds_h[ldr][c * 32 + lg * 8];
        short8v al0 = *(const short8v*)&lds_l[ldr][c * 32 + lg * 8];
        const unsigned short* bph = Bh + ((size_t)(c * 7) * 64 + lane) * 8;
        const unsigned short* bpl = Bl + ((size_t)(c * 7) * 64 + lane) * 8;
#pragma unroll
        for (int nt = 0; nt < 7; ++nt) {
            short8v bh = *(const short8v*)(bph + nt * 512);
            short8v bl = *(const short8v*)(bpl + nt * 512);
            acc[nt] = MF(ah0, bh, acc[nt]);
            acc[nt] = MF(ah0, bl, acc[nt]);
            acc[nt] = MF(al0, bh, acc[nt]);
        }
    }
    // part 1: x @ Wr (A-frags from global planes)
#pragma unroll
    for (int c = 0; c < 4; ++c) {
        short8v ah0 = *(const short8v*)(Xhi + b0 + c * 32);
        short8v al0 = *(const short8v*)(Xlo + b0 + c * 32);
        const unsigned short* bph = Bh + ((size_t)((4 + c) * 7) * 64 + lane) * 8;
        const unsigned short* bpl = Bl + ((size_t)((4 + c) * 7) * 64 + lane) * 8;
#pragma unroll
        for (int nt = 0; nt < 7; ++nt) {
            short8v bh = *(const short8v*)(bph + nt * 512);
            short8v bl = *(const short8v*)(bpl + nt * 512);
            acc[nt] = MF(ah0, bh, acc[nt]);
            acc[nt] = MF(ah0, bl, acc[nt]);
            acc[nt] = MF(al0, bh, acc[nt]);
        }
    }

    // epilogue: C/D layout col=lane&15, row=(lane>>4)*4+reg  [HW-verified]
#pragma unroll
    for (int nt = 0; nt < 7; ++nt) {
        int col = nt * 16 + lrow;
        bool cok = col < 100;
        float bb = cok ? bias[col] : 0.f;
#pragma unroll
        for (int r = 0; r < 4; ++r) {
            int row = m0 + lg * 4 + r;
            if (cok && row < n) {
                float v = acc[nt][r] + bb;
                if (relu) v = fmaxf(v, 0.f);
                unsigned short h = f2bf(v);
                size_t o = (size_t)row * PST + col;
                Ohi[o] = h;
                Olo[o] = f2bf(v - bf2f(h));
            }
        }
    }
    // zero pad cols 100..127 (both planes); 2 lanes per row, 16 rows/wave
    if (lane < 32) {
        int row = m0 + (lane >> 1);
        if (row < n) {
            unsigned short* op = ((lane & 1) == 0 ? Ohi : Olo) + (size_t)row * PST;
            short4 z4 = {0, 0, 0, 0};
            short8v z = (short8v){0,0,0,0,0,0,0,0};
            *(short4*)(op + 100) = z4;
            *(short8v*)(op + 104) = z;
            *(short8v*)(op + 112) = z;
            *(short8v*)(op + 120) = z;
        }
    }
}

// ---------------- pool + head: 1 block/graph ----------------
__global__ __launch_bounds__(256) void k_pool(const unsigned short* __restrict__ Hhi,
                                              const unsigned short* __restrict__ Hlo,
                                              const int* __restrict__ batch,
                                              const float* __restrict__ Wlin,
                                              const float* __restrict__ blin,
                                              float* __restrict__ out, int n) {
    int g = blockIdx.x;
    int t = threadIdx.x;
    int grp = t >> 4, l = t & 15;
    int lo = 0, hi = n;
    while (lo < hi) { int m = (lo + hi) >> 1; if (batch[m] < g) lo = m + 1; else hi = m; }
    int lo2 = lo, hi2 = n;
    while (lo2 < hi2) { int m = (lo2 + hi2) >> 1; if (batch[m] < g + 1) lo2 = m + 1; else hi2 = m; }

    const bool act = l < 13;
    float a[8];
#pragma unroll
    for (int m = 0; m < 8; ++m) a[m] = 0.f;
    const size_t loff = (size_t)l * 8;
    for (int node = lo + grp; node < lo2; node += 16) {
        if (act) {
            short8v vh = *(const short8v*)(Hhi + (size_t)node * PST + loff);
            short8v vl = *(const short8v*)(Hlo + (size_t)node * PST + loff);
#pragma unroll
            for (int m = 0; m < 8; ++m)
                a[m] += bf2f((unsigned short)vh[m]) + bf2f((unsigned short)vl[m]);
        }
    }

    __shared__ float part[16][13][8];
    if (act) {
#pragma unroll
        for (int m = 0; m < 8; ++m) part[grp][l][m] = a[m];
    }
    __syncthreads();

    __shared__ float gm[104];
    if (t < 104) {
        int fg = t >> 3, m = t & 7;
        float s = 0.f;
#pragma unroll
        for (int q = 0; q < 16; ++q) s += part[q][fg][m];
        float f = (lo2 > lo) ? 1.0f / (float)(lo2 - lo) : 0.0f;
        gm[t] = s * f;
    }
    __syncthreads();
    if (t < 2) {
        float o = blin[t];
        for (int k = 0; k < 100; ++k) o += gm[k] * Wlin[k * 2 + t];
        out[g * 2 + t] = o;
    }
}

// ---------------- launch ----------------

extern "C" void kernel_launch(void* const* d_in, const int* in_sizes, int n_in,
                              void* d_out, int out_size, void* d_ws, size_t ws_size,
                              hipStream_t stream) {
    const float* x    = (const float*)d_in[0];
    const int*   ei   = (const int*)d_in[1];
    const int*   batch= (const int*)d_in[2];
    const float* W1l  = (const float*)d_in[3];
    const float* b1   = (const float*)d_in[4];
    const float* W1r  = (const float*)d_in[5];
    const float* W2l  = (const float*)d_in[6];
    const float* b2   = (const float*)d_in[7];
    const float* W2r  = (const float*)d_in[8];
    const float* W3l  = (const float*)d_in[9];
    const float* b3   = (const float*)d_in[10];
    const float* W3r  = (const float*)d_in[11];
    const float* Wlin = (const float*)d_in[12];
    const float* blin = (const float*)d_in[13];
    float* out = (float*)d_out;

    const int n_nodes  = in_sizes[0] / 100;
    const int n_edges  = in_sizes[1] / 2;
    const int n_graphs = out_size / 2;
    const int* src = ei;
    const int* dst = ei + n_edges;

    char* ws = (char*)d_ws;
    size_t o = 0;
    auto alloc = [&](size_t bytes) { size_t r = o; o = (o + bytes + 255) & ~(size_t)255; return r; };
    int*   rowp = (int*)(ws + alloc((size_t)(n_nodes + 1) * 4));
    float* inv  = (float*)(ws + alloc((size_t)n_nodes * 4));
    int*   ssrc = (int*)(ws + alloc((size_t)n_edges * 4));
    int*   bcnt = (int*)(ws + alloc(MAXBUCK * 4));
    int*   bbase= (int*)(ws + alloc(MAXBUCK * 4));
    int*   bcur = (int*)(ws + alloc(MAXBUCK * 4));
    int2*  tmpv = (int2*)(ws + alloc((size_t)n_edges * 8));
    const size_t pbytes = (size_t)n_nodes * PST * 2;  // one bf16 plane
    unsigned short* XAhi = (unsigned short*)(ws + alloc(pbytes));
    unsigned short* XAlo = (unsigned short*)(ws + alloc(pbytes));
    unsigned short* XBhi = (unsigned short*)(ws + alloc(pbytes));
    unsigned short* XBlo = (unsigned short*)(ws + alloc(pbytes));
    const size_t bfb = (size_t)PACKN * 8 * 2;
    unsigned short* B1h = (unsigned short*)(ws + alloc(bfb));
    unsigned short* B1l = (unsigned short*)(ws + alloc(bfb));
    unsigned short* B2h = (unsigned short*)(ws + alloc(bfb));
    unsigned short* B2l = (unsigned short*)(ws + alloc(bfb));
    unsigned short* B3h = (unsigned short*)(ws + alloc(bfb));
    unsigned short* B3l = (unsigned short*)(ws + alloc(bfb));

    hipMemsetAsync(bcnt, 0, MAXBUCK * 4, stream);

    const int nbuck = (n_nodes + 255) >> 8;
    const int chunk = (n_edges + 255) / 256;

    // bucket CSR build (no node-level global pass)
    k_bincount<<<256, 256, 0, stream>>>(dst, bcnt, n_edges, nbuck, chunk);
    k_binscan<<<1, 1024, 0, stream>>>(bcnt, bbase, bcur, rowp, nbuck, n_nodes, n_edges);
    k_binscatter<<<256, 256, 0, stream>>>(src, dst, bcur, tmpv, n_edges, nbuck, chunk);
    k_build<<<nbuck, 256, 0, stream>>>(tmpv, bbase, rowp, inv, ssrc,
                                       n_nodes, n_edges, nbuck);

    k_pack3<<<(3 * PACKN + 255) / 256, 256, 0, stream>>>(
        W1l, W1r, W2l, W2r, W3l, W3r, B1h, B1l, B2h, B2l, B3h, B3l);

    const int nb16 = (n_nodes + 15) / 16;
    const int lgrid = (n_nodes + 31) / 32;

    k_cvt<<<nb16, 256, 0, stream>>>(x, XAhi, XAlo, n_nodes);

    // fused layers: aggr(LDS) + gemm
    k_layer<<<lgrid, 128, 0, stream>>>(XAhi, XAlo, ssrc, rowp, inv, B1h, B1l, b1,
                                       XBhi, XBlo, 1, n_nodes);
    k_layer<<<lgrid, 128, 0, stream>>>(XBhi, XBlo, ssrc, rowp, inv, B2h, B2l, b2,
                                       XAhi, XAlo, 1, n_nodes);
    k_layer<<<lgrid, 128, 0, stream>>>(XAhi, XAlo, ssrc, rowp, inv, B3h, B3l, b3,
                                       XBhi, XBlo, 0, n_nodes);

    k_pool<<<n_graphs, 256, 0, stream>>>(XBhi, XBlo, batch, Wlin, blin, out, n_nodes);
}